// Round 9
// baseline (12664.064 us; speedup 1.0000x reference)
//
#include <hip/hip_runtime.h>
#include <math.h>

// GRU enc-dec w/ attention. B=32,S=512,T=128,V=128,L=5,E=512,H=1024,F=2048.
// R11: decoder per R10 counters (35.5us/step, Occupancy 12.4% = half the CUs
//     idle, HBM 1030GB/s, ~9us/barrier): (1) NBD 128->256 blocks (ALL CUs,
//     8 waves each; att 4 blk/batch, phase-B 128-col slices); (2) leader-
//     broadcast barrier: per-block release-STORE to own cacheline (parallel,
//     no RMW contention) + blk0 polls + 8 XCD-spread go words. Encoder gets
//     the same barrier (math untouched). Gates/GEMM/att order bit-identical;
//     phase-B ctx partials regrouped 16->32 (fp32, fixed order).

#define Bb 32
#define Ss 512
#define Tt 128
#define Vv 128
#define Hh 1024
#define H3 3072
#define APAD 40
#define NBE 64    // persistent encoder blocks
#define NBD 256   // persistent decoder blocks

typedef __attribute__((ext_vector_type(8))) short bf16x8;
typedef __attribute__((ext_vector_type(4))) float f32x4;

__device__ inline f32x4 mfma_bf16(bf16x8 a, bf16x8 b, f32x4 c) {
  return __builtin_amdgcn_mfma_f32_16x16x32_bf16(a, b, c, 0, 0, 0);
}
__device__ inline unsigned short f2bf(float f) {
  unsigned u = __builtin_bit_cast(unsigned, f);
  unsigned r = (u + 0x7fffu + ((u >> 16) & 1u)) >> 16;
  return (unsigned short)r;
}
__device__ inline float lof(unsigned u) { return __builtin_bit_cast(float, u << 16); }
__device__ inline float hif(unsigned u) { return __builtin_bit_cast(float, u & 0xffff0000u); }
__device__ inline float bf2f(unsigned short h) {
  return __builtin_bit_cast(float, ((unsigned)h) << 16);
}

// ---------------- workspace offsets (BYTES) ----------------
#define O_ESBF   0UL            // es bf16      [B*S][1024]  32MB
#define O_ESQ    33554432UL     // esq bf16     [B*S][1024]  32MB  (aliased: G1 in MLP)
#define O_AVBF   67108864UL     // av bf16      [B*S][1024]  32MB  (aliased: G2 in MLP)
#define O_HCBF   100663296UL    // hc bf16      [T*B][1024]   8MB
#define O_WHE    109051904UL    // enc_Wh bf16  [3072][1024]  6MB
#define O_WHD    115343360UL    // dec_Wh bf16  6MB
#define O_WIC    121634816UL    // dec_Wi ctx-cols bf16 [3072][1024] 6MB
#define O_WKB    127926272UL    // Wk bf16 [1024][1024] 2MB
#define O_WQT    130023424UL    // Wq^T bf16 [1024][1024] 2MB
#define O_W1B    132120576UL    // W1 bf16 [4096][1024] 8MB
#define O_W2B    140509184UL    // W2 bf16 [2048][4096] 16MB
#define O_W3B    157286400UL    // W3 bf16 [128][2048] 0.5MB
#define O_XCAT   157810688UL    // fp32 [640][1024]
#define O_EMBFC  160432128UL    // fp32 [640][512]
#define O_GITAB  161742848UL    // fp32 [640][3072]
#define O_AVTAB  169607168UL    // fp32 [640][1024]
#define O_DGIXT  172228608UL    // fp32 [128][3072]
#define O_GH     173801472UL    // fp32 [32][3072]
#define O_GI     174194688UL    // 384KB: cltab(64KB)+hbf2(64KB)+bars(~22KB)
#define O_H      174587904UL    // fp32 [32][1024]
#define O_HBF    174718976UL    // bf16 [32][1024]
#define O_CTX    174784512UL    // fp32 [32][1024]
#define O_CTXBF  174915584UL    // bf16 [32][1024]
#define O_ATTL   174981120UL    // fp32 [32][512]
// total ~167MB

// bar layout (ints): [0..4095] dec arr (256x16), [4096..4223] dec go (8x16),
// [4224..5247] enc arr (64x16), [5248..5375] enc go (8x16)
#define BAR_N 5376

// ---------------- setup helpers ----------------
__global__ void k_xcat(const float* __restrict__ ce, const float* __restrict__ le,
                       float* __restrict__ xcat) {
  int row = blockIdx.x;  // l*128 + c
  int l = row >> 7, c = row & 127;
  int i = threadIdx.x * 4;
  float4 v;
  if (i < 512) v = *(const float4*)(ce + c * 512 + i);
  else         v = *(const float4*)(le + l * 512 + (i - 512));
  *(float4*)(xcat + (size_t)row * 1024 + i) = v;
}

__global__ void k_cltab(const int* __restrict__ sc, const int* __restrict__ sl,
                        int* __restrict__ cl, int* __restrict__ bar) {
  if (blockIdx.x == 0) {
    for (int i2 = threadIdx.x; i2 < BAR_N; i2 += 256) bar[i2] = 0;
  }
  int i = blockIdx.x * 256 + threadIdx.x;  // 16384 = 32b * 512s
  int b = i >> 9, s = i & 511;
  cl[s * 32 + b] = sl[b * Ss + s] * 128 + sc[b * Ss + s];
}

__global__ void k_cvt(const float* __restrict__ src, int ld, int lc,
                      unsigned short* __restrict__ dst) {
  size_t i = ((size_t)blockIdx.x * 256 + threadIdx.x) * 8;
  size_t r = i >> lc;
  int c = (int)(i & ((1u << lc) - 1));
  const float* s = src + r * (size_t)ld + c;
  float4 v0 = *(const float4*)s;
  float4 v1 = *(const float4*)(s + 4);
  union { unsigned short us[8]; uint4 u; } o;
  o.us[0] = f2bf(v0.x); o.us[1] = f2bf(v0.y); o.us[2] = f2bf(v0.z); o.us[3] = f2bf(v0.w);
  o.us[4] = f2bf(v1.x); o.us[5] = f2bf(v1.y); o.us[6] = f2bf(v1.z); o.us[7] = f2bf(v1.w);
  *(uint4*)(dst + i) = o.u;
}

__global__ void k_transcvt(const float* __restrict__ in, unsigned short* __restrict__ out) {
  __shared__ float t[32][33];
  int c0 = blockIdx.x * 32, r0 = blockIdx.y * 32;
  int tx = threadIdx.x, ty = threadIdx.y;
  for (int i = ty; i < 32; i += 8)
    t[i][tx] = in[(size_t)(r0 + i) * 1024 + c0 + tx];
  __syncthreads();
  for (int i = ty; i < 32; i += 8)
    out[(size_t)(c0 + i) * 1024 + r0 + tx] = f2bf(t[tx][i]);
}

// ---------------- fp32 tiled GEMM (setup tables only): C=A@W^T ----------------
template <bool BIAS>
__global__ __launch_bounds__(256) void k_gemm(
    const float* __restrict__ A, int lda, const float* __restrict__ W, int ldw,
    const float* __restrict__ bias, float* __restrict__ C, int ldc, int K) {
  __shared__ float As[8][128];
  __shared__ float Ws[8][128];
  int tid = threadIdx.x;
  int n0 = blockIdx.x * 128, m0 = blockIdx.y * 128;
  int tx = tid & 15, ty = tid >> 4;
  int lrow = tid >> 1, lseg = (tid & 1) * 4;
  const float* Ap = A + (size_t)(m0 + lrow) * lda + lseg;
  const float* Wp = W + (size_t)(n0 + lrow) * ldw + lseg;
  float acc[8][8];
#pragma unroll
  for (int i = 0; i < 8; ++i)
#pragma unroll
    for (int j = 0; j < 8; ++j) acc[i][j] = 0.f;
  for (int kt = 0; kt < K; kt += 8) {
    float4 av = *(const float4*)(Ap + kt);
    float4 wv = *(const float4*)(Wp + kt);
    __syncthreads();
    As[lseg + 0][lrow] = av.x; As[lseg + 1][lrow] = av.y;
    As[lseg + 2][lrow] = av.z; As[lseg + 3][lrow] = av.w;
    Ws[lseg + 0][lrow] = wv.x; Ws[lseg + 1][lrow] = wv.y;
    Ws[lseg + 2][lrow] = wv.z; Ws[lseg + 3][lrow] = wv.w;
    __syncthreads();
#pragma unroll
    for (int kk = 0; kk < 8; ++kk) {
      float a[8], b[8];
      *(float4*)(a + 0) = *(const float4*)(&As[kk][ty * 8 + 0]);
      *(float4*)(a + 4) = *(const float4*)(&As[kk][ty * 8 + 4]);
      *(float4*)(b + 0) = *(const float4*)(&Ws[kk][tx * 8 + 0]);
      *(float4*)(b + 4) = *(const float4*)(&Ws[kk][tx * 8 + 4]);
#pragma unroll
      for (int i = 0; i < 8; ++i)
#pragma unroll
        for (int j = 0; j < 8; ++j) acc[i][j] = fmaf(a[i], b[j], acc[i][j]);
    }
  }
#pragma unroll
  for (int i = 0; i < 8; ++i) {
    int r = m0 + ty * 8 + i;
#pragma unroll
    for (int j = 0; j < 8; ++j) {
      int c = n0 + tx * 8 + j;
      float v = acc[i][j];
      if (BIAS) v += bias[c];
      C[(size_t)r * ldc + c] = v;
    }
  }
}

// ---------------- bf16 MFMA GEMM: C[M,N] = A[M,K] @ W[N,K]^T ----------------
// EPI: 0 store bf16; 1 +=avtab[lang*128+char][col], store bf16; 2 fp32 scatter to out
template <int EPI, bool RELU, bool BIAS>
__global__ __launch_bounds__(256) void k_bgemm(
    const unsigned short* __restrict__ A, int lda,
    const unsigned short* __restrict__ W, int ldw,
    const float* __restrict__ bias, void* __restrict__ Cout, int ldc, int K,
    const float* __restrict__ avtab, const int* __restrict__ gl,
    const int* __restrict__ gc) {
  __shared__ unsigned short As[128 * APAD];
  __shared__ unsigned short Bs[128 * APAD];
  int tid = threadIdx.x;
  int n0 = blockIdx.x * 128, m0 = blockIdx.y * 128;
  int w = tid >> 6, l = tid & 63;
  int mw = (w & 1) * 64, nw = (w >> 1) * 64;
  int lrow = tid >> 1, lk = (tid & 1) * 16;
  const unsigned short* Ap = A + (size_t)(m0 + lrow) * lda + lk;
  const unsigned short* Wp = W + (size_t)(n0 + lrow) * ldw + lk;
  int fr = l & 15, fk = (l >> 4) * 8;
  f32x4 acc[4][4];
#pragma unroll
  for (int i = 0; i < 4; ++i)
#pragma unroll
    for (int j = 0; j < 4; ++j) acc[i][j] = (f32x4){0.f, 0.f, 0.f, 0.f};
  for (int kt = 0; kt < K; kt += 32) {
    uint4 a0 = *(const uint4*)(Ap + kt);
    uint4 a1 = *(const uint4*)(Ap + kt + 8);
    uint4 b0 = *(const uint4*)(Wp + kt);
    uint4 b1 = *(const uint4*)(Wp + kt + 8);
    __syncthreads();
    *(uint4*)&As[lrow * APAD + lk] = a0;
    *(uint4*)&As[lrow * APAD + lk + 8] = a1;
    *(uint4*)&Bs[lrow * APAD + lk] = b0;
    *(uint4*)&Bs[lrow * APAD + lk + 8] = b1;
    __syncthreads();
    bf16x8 af[4], bfg[4];
#pragma unroll
    for (int i = 0; i < 4; ++i) af[i] = *(const bf16x8*)&As[(mw + i * 16 + fr) * APAD + fk];
#pragma unroll
    for (int j = 0; j < 4; ++j) bfg[j] = *(const bf16x8*)&Bs[(nw + j * 16 + fr) * APAD + fk];
#pragma unroll
    for (int i = 0; i < 4; ++i)
#pragma unroll
      for (int j = 0; j < 4; ++j) acc[i][j] = mfma_bf16(af[i], bfg[j], acc[i][j]);
  }
#pragma unroll
  for (int i = 0; i < 4; ++i)
#pragma unroll
    for (int j = 0; j < 4; ++j) {
      int col = n0 + nw + j * 16 + fr;
#pragma unroll
      for (int r = 0; r < 4; ++r) {
        int row = m0 + mw + i * 16 + (l >> 4) * 4 + r;
        float v = acc[i][j][r];
        if (BIAS) v += bias[col];
        if (RELU) v = fmaxf(v, 0.f);
        if (EPI == 0) {
          ((unsigned short*)Cout)[(size_t)row * ldc + col] = f2bf(v);
        } else if (EPI == 1) {
          int cl = gl[row] * 128 + gc[row];
          ((unsigned short*)Cout)[(size_t)row * ldc + col] =
              f2bf(v + avtab[(size_t)cl * 1024 + col]);
        } else {
          int tt = row >> 5, bb = row & 31;
          ((float*)Cout)[(size_t)bb * (Tt * Vv) + tt * Vv + col] = v;
        }
      }
    }
}

// ---------------- persistent encoder scan (R7 math; leader barrier) ---------
__global__ __launch_bounds__(512) void k_enc_pers(
    const unsigned short* __restrict__ Whe, const float* __restrict__ gitab,
    const int* __restrict__ cltab, const float* __restrict__ bh,
    float* __restrict__ h, unsigned short* __restrict__ hbf0,
    unsigned short* __restrict__ hbf1, unsigned short* __restrict__ esb,
    int* __restrict__ bar) {
  __shared__ unsigned short Ws[48 * 1024];  // 96KB
  __shared__ f32x4 red[8 * 6 * 64];         // 48KB
  int* earr = bar;           // 64x16
  int* ego  = bar + 1024;    // 8x16
  int tid = threadIdx.x;
  int blk = blockIdx.x;
  int w = tid >> 6, l = tid & 63;
  int fr = l & 15, q = l >> 4;
  int j = blk * 16 + fr;
  {  // stage 48 Wh rows, XOR-swizzled per 16B chunk
    uint4* dst = (uint4*)Ws;
    const uint4* src = (const uint4*)Whe;
#pragma unroll
    for (int it = 0; it < 12; ++it) {
      int idx = it * 512 + tid;           // 0..6143
      int lr = idx >> 7, c = idx & 127;   // local row, chunk
      int grow = (lr >> 4) * 1024 + blk * 16 + (lr & 15);
      dst[lr * 128 + (c ^ (lr & 7))] = src[(size_t)grow * 128 + c];
    }
  }
  float bhr = bh[j], bhz = bh[1024 + j], bhn = bh[2048 + j];
  float hold[4] = {0.f, 0.f, 0.f, 0.f};
  __syncthreads();
  const bf16x8* Wsv = (const bf16x8*)Ws;
  int bc = 0;
  for (int s = 0; s < Ss; ++s) {
    unsigned short* wb = (s & 1) ? hbf1 : hbf0;
    const unsigned short* rb = (s & 1) ? hbf0 : hbf1;
    float gi0[4], gi1[4], gi2[4];
    if (w < 2) {
#pragma unroll
      for (int r = 0; r < 4; ++r) {
        int b = w * 16 + q * 4 + r;
        int c = cltab[s * 32 + b];
        const float* gp = gitab + (size_t)c * H3 + j;
        gi0[r] = gp[0]; gi1[r] = gp[1024]; gi2[r] = gp[2048];
      }
    }
    f32x4 acc[2][3];
#pragma unroll
    for (int m = 0; m < 2; ++m)
#pragma unroll
      for (int g = 0; g < 3; ++g) acc[m][g] = (f32x4){0.f, 0.f, 0.f, 0.f};
    if (s > 0) {
      int kb = w * 128 + q * 8;
      const unsigned short* A0 = rb + fr * 1024 + kb;
#pragma unroll
      for (int kt = 0; kt < 128; kt += 32) {
        bf16x8 a0 = *(const bf16x8*)(A0 + kt);
        bf16x8 a1 = *(const bf16x8*)(A0 + 16 * 1024 + kt);
        int c8 = (kb + kt) >> 3;
#pragma unroll
        for (int g = 0; g < 3; ++g) {
          bf16x8 bw = Wsv[(g * 16 + fr) * 128 + (c8 ^ (fr & 7))];
          acc[0][g] = mfma_bf16(a0, bw, acc[0][g]);
          acc[1][g] = mfma_bf16(a1, bw, acc[1][g]);
        }
      }
    }
#pragma unroll
    for (int m = 0; m < 2; ++m)
#pragma unroll
      for (int g = 0; g < 3; ++g)
        red[(w * 6 + m * 3 + g) * 64 + l] = acc[m][g];
    __syncthreads();
    if (w < 2) {
      int m = w;
      f32x4 as_[3];
#pragma unroll
      for (int g = 0; g < 3; ++g) as_[g] = (f32x4){0.f, 0.f, 0.f, 0.f};
#pragma unroll
      for (int ww = 0; ww < 8; ++ww)
#pragma unroll
        for (int g = 0; g < 3; ++g)
          as_[g] = as_[g] + red[(ww * 6 + m * 3 + g) * 64 + l];
#pragma unroll
      for (int r = 0; r < 4; ++r) {
        int b = m * 16 + q * 4 + r;
        float ghr = bhr + as_[0][r], ghz = bhz + as_[1][r], ghn = bhn + as_[2][r];
        float rg = 1.f / (1.f + expf(-(gi0[r] + ghr)));
        float zg = 1.f / (1.f + expf(-(gi1[r] + ghz)));
        float ng = tanhf(gi2[r] + rg * ghn);
        float hn = (1.f - zg) * ng + zg * hold[r];
        hold[r] = hn;
        unsigned short hb = f2bf(hn);
        wb[b * 1024 + j] = hb;
        esb[((size_t)b * Ss + s) * 1024 + j] = hb;
        if (s == Ss - 1) h[b * 1024 + j] = hn;
      }
    }
    // leader-broadcast barrier
    __syncthreads();
    ++bc;
    if (tid == 0)
      __hip_atomic_store(&earr[blk * 16], bc, __ATOMIC_RELEASE, __HIP_MEMORY_SCOPE_AGENT);
    if (blk == 0) {
      if (tid < NBE) {
        while (__hip_atomic_load(&earr[tid * 16], __ATOMIC_RELAXED,
                                 __HIP_MEMORY_SCOPE_AGENT) < bc)
          __builtin_amdgcn_s_sleep(1);
      }
      __syncthreads();
      if (tid == 0) {
        __builtin_amdgcn_fence(__ATOMIC_ACQUIRE, "agent");
        for (int x = 0; x < 8; ++x)
          __hip_atomic_store(&ego[x * 16], bc, __ATOMIC_RELEASE, __HIP_MEMORY_SCOPE_AGENT);
      }
    }
    if (tid == 0) {
      while (__hip_atomic_load(&ego[(blk & 7) * 16], __ATOMIC_RELAXED,
                               __HIP_MEMORY_SCOPE_AGENT) < bc)
        __builtin_amdgcn_s_sleep(1);
      __builtin_amdgcn_fence(__ATOMIC_ACQUIRE, "agent");
    }
    __syncthreads();
  }
}

// ---------------- persistent decoder (R11) ----------------
// 256 blocks x 512 thr (ALL CUs, 8 waves each). Leader-broadcast barrier.
// blk 0-63:   Whd slice in LDS. A: gh GEMM (8-wave split-K, encoder order).
// blk 64-127: Wic slice in LDS. C: gi GEMM + gates. (idle in A)
// blk 128-255: A: attention (batch=(blk-128)>>2, quarter aq=(blk-128)&3;
//             per-s dot order identical to R8/R10) + hc-fold.
// all:        B: softmax (exact k_ctxsm order) + vectorized w@av
//             (128-col slice/block; 32 s-groups x 16 lanes; fp32 LDS reduce).
__global__ __launch_bounds__(512) void k_dec_pers(
    const unsigned short* __restrict__ Whd, const unsigned short* __restrict__ Wic,
    const unsigned short* __restrict__ esq, const unsigned short* __restrict__ av,
    const float* __restrict__ dgixt, const int* __restrict__ tgt,
    const float* __restrict__ bh, float* __restrict__ h,
    unsigned short* __restrict__ hbf, float* __restrict__ ctx,
    unsigned short* __restrict__ ctxbf, float* __restrict__ attL,
    float* __restrict__ ghbuf, unsigned short* __restrict__ hcbf,
    int* __restrict__ bar) {
  __shared__ unsigned short Ws[48 * 1024];  // 96KB weight slice (blk<128)
  __shared__ float scr[12 * 1024];          // 48KB: red (gemm) / partials (B)
  __shared__ float hs[1024];                // 4KB h stage (att)
  __shared__ float wS[512];
  __shared__ float wm[4], wsm[4];
  f32x4* red = (f32x4*)scr;
  int* darr = bar;          // 256x16
  int* dgo  = bar + 4096;   // 8x16
  int tid = threadIdx.x;
  int blk = blockIdx.x;
  int wv = tid >> 6, l = tid & 63;
  int fr = l & 15, q = l >> 4;
  int rnd = 0;
  bool isGH = blk < 64;
  bool isGI = (blk >= 64 && blk < 128);
  // ---- stage weight slice once (gh: Whd, gi: Wic), XOR-swizzled ----
  int jsl = (blk & 63) * 16;
  if (blk < 128) {
    const uint4* src = (const uint4*)(isGH ? Whd : Wic);
    uint4* dst = (uint4*)Ws;
#pragma unroll
    for (int it = 0; it < 12; ++it) {
      int idx = it * 512 + tid;           // 0..6143
      int lr = idx >> 7, c = idx & 127;
      int grow = (lr >> 4) * 1024 + jsl + (lr & 15);
      dst[lr * 128 + (c ^ (lr & 7))] = src[(size_t)grow * 128 + c];
    }
  }
  const bf16x8* Wsv = (const bf16x8*)Ws;
  int jw = jsl + fr;
  float bhr = bh[jw], bhz = bh[1024 + jw], bhn = bh[2048 + jw];
  int batch = (blk - 128) >> 2, aq = (blk - 128) & 3;  // att-role mapping
  int b2 = blk >> 3, jq = blk & 7;                     // ctxsm-role mapping

#define GBAR()                                                                          \
  do {                                                                                  \
    __syncthreads();                                                                    \
    ++rnd;                                                                              \
    if (tid == 0)                                                                       \
      __hip_atomic_store(&darr[blk * 16], rnd, __ATOMIC_RELEASE,                        \
                         __HIP_MEMORY_SCOPE_AGENT);                                     \
    if (blk == 0) {                                                                     \
      if (tid < NBD) {                                                                  \
        while (__hip_atomic_load(&darr[tid * 16], __ATOMIC_RELAXED,                     \
                                 __HIP_MEMORY_SCOPE_AGENT) < rnd)                       \
          __builtin_amdgcn_s_sleep(1);                                                  \
      }                                                                                 \
      __syncthreads();                                                                  \
      if (tid == 0) {                                                                   \
        __builtin_amdgcn_fence(__ATOMIC_ACQUIRE, "agent");                              \
        for (int x = 0; x < 8; ++x)                                                     \
          __hip_atomic_store(&dgo[x * 16], rnd, __ATOMIC_RELEASE,                       \
                             __HIP_MEMORY_SCOPE_AGENT);                                 \
      }                                                                                 \
    }                                                                                   \
    if (tid == 0) {                                                                     \
      while (__hip_atomic_load(&dgo[(blk & 7) * 16], __ATOMIC_RELAXED,                  \
                               __HIP_MEMORY_SCOPE_AGENT) < rnd)                         \
        __builtin_amdgcn_s_sleep(1);                                                    \
      __builtin_amdgcn_fence(__ATOMIC_ACQUIRE, "agent");                                \
    }                                                                                   \
    __syncthreads();                                                                    \
  } while (0)

  // ---- init: ctx = enc final h (blocks 0-127 cover 32x1024) ----
  if (blk < 128 && tid < 256) {
    int idx = blk * 256 + tid;
    float v = h[idx];
    ctx[idx] = v;
    ctxbf[idx] = f2bf(v);
  }
  GBAR();
  // ---- init: h0 = gru(0, [start_emb, ctx0]) (gi blocks; hzero, char=1) ----
  if (isGI) {
    f32x4 acc[2][3];
#pragma unroll
    for (int m = 0; m < 2; ++m)
#pragma unroll
      for (int g = 0; g < 3; ++g) acc[m][g] = (f32x4){0.f, 0.f, 0.f, 0.f};
    int kb = wv * 128 + q * 8;
    const unsigned short* A0 = ctxbf + fr * 1024 + kb;
#pragma unroll
    for (int kt = 0; kt < 128; kt += 32) {
      bf16x8 a0 = *(const bf16x8*)(A0 + kt);
      bf16x8 a1 = *(const bf16x8*)(A0 + 16 * 1024 + kt);
      int c8 = (kb + kt) >> 3;
#pragma unroll
      for (int g = 0; g < 3; ++g) {
        bf16x8 bw = Wsv[(g * 16 + fr) * 128 + (c8 ^ (fr & 7))];
        acc[0][g] = mfma_bf16(a0, bw, acc[0][g]);
        acc[1][g] = mfma_bf16(a1, bw, acc[1][g]);
      }
    }
#pragma unroll
    for (int m = 0; m < 2; ++m)
#pragma unroll
      for (int g = 0; g < 3; ++g)
        red[(wv * 6 + m * 3 + g) * 64 + l] = acc[m][g];
    __syncthreads();
    if (wv < 2) {
      int m = wv;
      f32x4 as_[3];
#pragma unroll
      for (int g = 0; g < 3; ++g) as_[g] = (f32x4){0.f, 0.f, 0.f, 0.f};
#pragma unroll
      for (int ww = 0; ww < 8; ++ww)
#pragma unroll
        for (int g = 0; g < 3; ++g)
          as_[g] = as_[g] + red[(ww * 6 + m * 3 + g) * 64 + l];
      const float* gp = dgixt + (size_t)1 * H3 + jw;  // start char = 1
#pragma unroll
      for (int r = 0; r < 4; ++r) {
        int b = m * 16 + q * 4 + r;
        float gir = gp[0] + as_[0][r];
        float giz = gp[1024] + as_[1][r];
        float gin = gp[2048] + as_[2][r];
        float rg = 1.f / (1.f + expf(-(gir + bhr)));
        float zg = 1.f / (1.f + expf(-(giz + bhz)));
        float ng = tanhf(gin + rg * bhn);
        float hn = (1.f - zg) * ng;  // hold = 0
        h[b * 1024 + jw] = hn;
        hbf[b * 1024 + jw] = f2bf(hn);
      }
    }
  }
  GBAR();
  // ---- main loop ----
  for (int t = 0; t < Tt; ++t) {
    // ===== phase A: gh GEMM (blk<64) | attention + hc-fold (blk>=128) =====
    if (isGH) {
      f32x4 acc[2][3];
#pragma unroll
      for (int m = 0; m < 2; ++m)
#pragma unroll
        for (int g = 0; g < 3; ++g) acc[m][g] = (f32x4){0.f, 0.f, 0.f, 0.f};
      int kb = wv * 128 + q * 8;
      const unsigned short* A0 = hbf + fr * 1024 + kb;
#pragma unroll
      for (int kt = 0; kt < 128; kt += 32) {
        bf16x8 a0 = *(const bf16x8*)(A0 + kt);
        bf16x8 a1 = *(const bf16x8*)(A0 + 16 * 1024 + kt);
        int c8 = (kb + kt) >> 3;
#pragma unroll
        for (int g = 0; g < 3; ++g) {
          bf16x8 bw = Wsv[(g * 16 + fr) * 128 + (c8 ^ (fr & 7))];
          acc[0][g] = mfma_bf16(a0, bw, acc[0][g]);
          acc[1][g] = mfma_bf16(a1, bw, acc[1][g]);
        }
      }
#pragma unroll
      for (int m = 0; m < 2; ++m)
#pragma unroll
        for (int g = 0; g < 3; ++g)
          red[(wv * 6 + m * 3 + g) * 64 + l] = acc[m][g];
      __syncthreads();
      if (wv < 2) {
        int m = wv;
        f32x4 as_[3];
#pragma unroll
        for (int g = 0; g < 3; ++g) as_[g] = (f32x4){0.f, 0.f, 0.f, 0.f};
#pragma unroll
        for (int ww = 0; ww < 8; ++ww)
#pragma unroll
          for (int g = 0; g < 3; ++g)
            as_[g] = as_[g] + red[(ww * 6 + m * 3 + g) * 64 + l];
#pragma unroll
        for (int r = 0; r < 4; ++r) {
          int b = m * 16 + q * 4 + r;
#pragma unroll
          for (int g = 0; g < 3; ++g)
            ghbuf[b * H3 + g * 1024 + jw] = as_[g][r];
        }
      }
    } else if (blk >= 128) {
      for (int i = tid; i < 1024; i += 512) hs[i] = h[batch * 1024 + i];
      __syncthreads();
      if (tid < 256) {  // hc fold: this block covers j = aq*256 .. aq*256+255
        int j2 = aq * 256 + tid;
        hcbf[(size_t)t * (Bb * Hh) + batch * 1024 + j2] =
            f2bf(hs[j2] + ctx[batch * 1024 + j2]);
      }
      int sg = tid >> 2, li = tid & 3;  // sg 0..127
      int s0 = aq * 128 + sg;
      const unsigned short* ep0 = esq + (size_t)(batch * 512 + s0) * 1024;
      float acc0 = 0.f;
#pragma unroll 8
      for (int i = 0; i < 32; ++i) {
        int k = (i * 4 + li) * 8;
        uint4 e0 = *(const uint4*)(ep0 + k);
        float4 h0 = *(const float4*)&hs[k];
        float4 h1 = *(const float4*)&hs[k + 4];
        acc0 += lof(e0.x) * h0.x + hif(e0.x) * h0.y + lof(e0.y) * h0.z + hif(e0.y) * h0.w +
                lof(e0.z) * h1.x + hif(e0.z) * h1.y + lof(e0.w) * h1.z + hif(e0.w) * h1.w;
      }
      acc0 += __shfl_xor(acc0, 1);
      acc0 += __shfl_xor(acc0, 2);
      if (li == 0) attL[batch * 512 + s0] = acc0;
    }
    if (t == Tt - 1) break;
    GBAR();
    // ===== phase B: softmax (uniform barriers) + vectorized ctx =====
    {
      float a0 = 0.f, a1 = 0.f;
      if (tid < 256) {
        a0 = attL[b2 * Ss + tid * 2];
        a1 = attL[b2 * Ss + tid * 2 + 1];
        float m = fmaxf(a0, a1);
        for (int d = 1; d < 64; d <<= 1) m = fmaxf(m, __shfl_xor(m, d));
        if ((tid & 63) == 0) wm[tid >> 6] = m;
      }
      __syncthreads();
      if (tid < 256) {
        float m = fmaxf(fmaxf(wm[0], wm[1]), fmaxf(wm[2], wm[3]));
        float e0 = expf(a0 - m), e1 = expf(a1 - m);
        wS[tid * 2] = e0;
        wS[tid * 2 + 1] = e1;
        float ssum = e0 + e1;
        for (int d = 1; d < 64; d <<= 1) ssum += __shfl_xor(ssum, d);
        if ((tid & 63) == 0) wsm[tid >> 6] = ssum;
      }
      __syncthreads();
      float scale = 1.f / (wsm[0] + wsm[1] + wsm[2] + wsm[3]);
      int g = tid & 15, si = tid >> 4;  // 16 lanes x 8 cols = 128-col slice
      const unsigned short* avp = av + (size_t)(b2 * 512) * 1024 + jq * 128 + g * 8;
      float a8[8] = {0.f, 0.f, 0.f, 0.f, 0.f, 0.f, 0.f, 0.f};
#pragma unroll 4
      for (int s = si; s < 512; s += 32) {
        float wv2 = wS[s];
        uint4 e = *(const uint4*)(avp + (size_t)s * 1024);
        a8[0] += wv2 * lof(e.x); a8[1] += wv2 * hif(e.x);
        a8[2] += wv2 * lof(e.y); a8[3] += wv2 * hif(e.y);
        a8[4] += wv2 * lof(e.z); a8[5] += wv2 * hif(e.z);
        a8[6] += wv2 * lof(e.w); a8[7] += wv2 * hif(e.w);
      }
      __syncthreads();  // scr free (phase A's red use done)
#pragma unroll
      for (int k2 = 0; k2 < 8; ++k2) scr[tid * 8 + k2] = a8[k2];
      __syncthreads();
      if (tid < 128) {
        int g2 = tid >> 3, k2 = tid & 7;
        float p = 0.f;
#pragma unroll
        for (int si2 = 0; si2 < 32; ++si2) p += scr[(si2 * 16 + g2) * 8 + k2];
        float v = p * scale;
        int j3 = b2 * 1024 + jq * 128 + tid;
        ctx[j3] = v;
        ctxbf[j3] = f2bf(v);
      }
    }
    GBAR();
    // ===== phase C: gi GEMM + gates (blk 64-127) =====
    if (isGI) {
      f32x4 acc[2][3];
#pragma unroll
      for (int m = 0; m < 2; ++m)
#pragma unroll
        for (int g = 0; g < 3; ++g) acc[m][g] = (f32x4){0.f, 0.f, 0.f, 0.f};
      int kb = wv * 128 + q * 8;
      const unsigned short* A0 = ctxbf + fr * 1024 + kb;
#pragma unroll
      for (int kt = 0; kt < 128; kt += 32) {
        bf16x8 a0 = *(const bf16x8*)(A0 + kt);
        bf16x8 a1 = *(const bf16x8*)(A0 + 16 * 1024 + kt);
        int c8 = (kb + kt) >> 3;
#pragma unroll
        for (int g = 0; g < 3; ++g) {
          bf16x8 bw = Wsv[(g * 16 + fr) * 128 + (c8 ^ (fr & 7))];
          acc[0][g] = mfma_bf16(a0, bw, acc[0][g]);
          acc[1][g] = mfma_bf16(a1, bw, acc[1][g]);
        }
      }
#pragma unroll
      for (int m = 0; m < 2; ++m)
#pragma unroll
        for (int g = 0; g < 3; ++g)
          red[(wv * 6 + m * 3 + g) * 64 + l] = acc[m][g];
      __syncthreads();
      if (wv < 2) {
        int m = wv;
        f32x4 as_[3];
#pragma unroll
        for (int g = 0; g < 3; ++g) as_[g] = (f32x4){0.f, 0.f, 0.f, 0.f};
#pragma unroll
        for (int ww = 0; ww < 8; ++ww)
#pragma unroll
          for (int g = 0; g < 3; ++g)
            as_[g] = as_[g] + red[(ww * 6 + m * 3 + g) * 64 + l];
#pragma unroll
        for (int r = 0; r < 4; ++r) {
          int b = m * 16 + q * 4 + r;
          int c = tgt[b * Tt + t];
          const float* gp = dgixt + (size_t)c * H3 + jw;
          float gir = gp[0] + as_[0][r];
          float giz = gp[1024] + as_[1][r];
          float gin = gp[2048] + as_[2][r];
          const float* g2 = ghbuf + b * H3 + jw;
          float ghr = bhr + g2[0];
          float ghz = bhz + g2[1024];
          float ghn = bhn + g2[2048];
          float rg = 1.f / (1.f + expf(-(gir + ghr)));
          float zg = 1.f / (1.f + expf(-(giz + ghz)));
          float ng = tanhf(gin + rg * ghn);
          float hn = (1.f - zg) * ng + zg * h[b * 1024 + jw];
          h[b * 1024 + jw] = hn;
          hbf[b * 1024 + jw] = f2bf(hn);
        }
      }
    }
    GBAR();
  }
#undef GBAR
}

// ---------------- host ----------------
extern "C" void kernel_launch(void* const* d_in, const int* in_sizes, int n_in,
                              void* d_out, int out_size, void* d_ws, size_t ws_size,
                              hipStream_t stream) {
  (void)in_sizes; (void)n_in; (void)out_size; (void)ws_size;
  const int*   src_chars = (const int*)d_in[0];
  const int*   src_langs = (const int*)d_in[1];
  const int*   tgt_chars = (const int*)d_in[2];
  const float* char_emb  = (const float*)d_in[3];
  const float* lang_emb  = (const float*)d_in[4];
  const float* fc_W  = (const float*)d_in[5];
  const float* fc_b  = (const float*)d_in[6];
  const float* enc_Wi = (const float*)d_in[7];
  const float* enc_Wh = (const float*)d_in[8];
  const float* enc_bi = (const float*)d_in[9];
  const float* enc_bh = (const float*)d_in[10];
  const float* dec_Wi = (const float*)d_in[11];
  const float* dec_Wh = (const float*)d_in[12];
  const float* dec_bi = (const float*)d_in[13];
  const float* dec_bh = (const float*)d_in[14];
  const float* Wq  = (const float*)d_in[15];
  const float* Wk  = (const float*)d_in[16];
  const float* Wcs = (const float*)d_in[17];
  const float* W1 = (const float*)d_in[18];
  const float* b1 = (const float*)d_in[19];
  const float* W2 = (const float*)d_in[20];
  const float* b2 = (const float*)d_in[21];
  const float* W3 = (const float*)d_in[22];
  float* out = (float*)d_out;

  char* ws = (char*)d_ws;
  unsigned short* esbf  = (unsigned short*)(ws + O_ESBF);
  unsigned short* esq   = (unsigned short*)(ws + O_ESQ);
  unsigned short* avbf  = (unsigned short*)(ws + O_AVBF);
  unsigned short* hcbf  = (unsigned short*)(ws + O_HCBF);
  unsigned short* WheB  = (unsigned short*)(ws + O_WHE);
  unsigned short* WhdB  = (unsigned short*)(ws + O_WHD);
  unsigned short* WicB  = (unsigned short*)(ws + O_WIC);
  unsigned short* WkB   = (unsigned short*)(ws + O_WKB);
  unsigned short* WqTB  = (unsigned short*)(ws + O_WQT);
  unsigned short* W1B   = (unsigned short*)(ws + O_W1B);
  unsigned short* W2B   = (unsigned short*)(ws + O_W2B);
  unsigned short* W3B   = (unsigned short*)(ws + O_W3B);
  float* xcat   = (float*)(ws + O_XCAT);
  float* embfc  = (float*)(ws + O_EMBFC);
  float* gitab  = (float*)(ws + O_GITAB);
  float* avtab  = (float*)(ws + O_AVTAB);
  float* dgixt  = (float*)(ws + O_DGIXT);
  float* ghbuf  = (float*)(ws + O_GH);
  float* h      = (float*)(ws + O_H);
  unsigned short* hbf   = (unsigned short*)(ws + O_HBF);
  float* ctx    = (float*)(ws + O_CTX);
  unsigned short* ctxbf = (unsigned short*)(ws + O_CTXBF);
  float* attL   = (float*)(ws + O_ATTL);
  unsigned short* G1 = esq;   // alias: dead after decoder
  unsigned short* G2 = avbf;  // alias: dead after decoder
  int* cltab = (int*)(ws + O_GI);                               // 64KB
  unsigned short* hbf2 = (unsigned short*)(ws + O_GI + 65536);  // 64KB enc dbuf
  int* bar = (int*)(ws + O_GI + 131072);  // see BAR layout above

  dim3 blk(256);

  // ---- tables (fp32) ----
  k_xcat<<<640, blk, 0, stream>>>(char_emb, lang_emb, xcat);
  k_cltab<<<64, blk, 0, stream>>>(src_chars, src_langs, cltab, bar);
  k_gemm<true><<<dim3(4, 5), blk, 0, stream>>>(xcat, 1024, fc_W, 1024, fc_b, embfc, 512, 1024);
  k_gemm<true><<<dim3(24, 5), blk, 0, stream>>>(embfc, 512, enc_Wi, 512, enc_bi, gitab, H3, 512);
  k_gemm<false><<<dim3(8, 5), blk, 0, stream>>>(embfc, 512, Wcs, 512, nullptr, avtab, Hh, 512);
  k_gemm<true><<<dim3(24, 1), blk, 0, stream>>>(embfc + 512 * 512, 512, dec_Wi, 1536, dec_bi,
                                                dgixt, H3, 512);
  // ---- weight conversions ----
  k_cvt<<<1536, blk, 0, stream>>>(enc_Wh, 1024, 10, WheB);
  k_cvt<<<1536, blk, 0, stream>>>(dec_Wh, 1024, 10, WhdB);
  k_cvt<<<1536, blk, 0, stream>>>(dec_Wi + 512, 1536, 10, WicB);
  k_cvt<<<512,  blk, 0, stream>>>(Wk, 1024, 10, WkB);
  k_cvt<<<2048, blk, 0, stream>>>(W1, 1024, 10, W1B);
  k_cvt<<<4096, blk, 0, stream>>>(W2, 4096, 12, W2B);
  k_cvt<<<128,  blk, 0, stream>>>(W3, 2048, 11, W3B);
  k_transcvt<<<dim3(32, 32), dim3(32, 8), 0, stream>>>(Wq, WqTB);

  // ---- encoder scan: persistent cooperative kernel (leader barrier) ----
  {
    const unsigned short* p_whe = WheB;
    const float* p_git = gitab;
    const int* p_cl = cltab;
    const float* p_bh = enc_bh;
    float* p_h = h;
    unsigned short* p_h0 = hbf;
    unsigned short* p_h1 = hbf2;
    unsigned short* p_esb = esbf;
    int* p_bar = bar + 4224;  // enc arr + go
    void* kargs[] = {(void*)&p_whe, (void*)&p_git, (void*)&p_cl, (void*)&p_bh,
                     (void*)&p_h, (void*)&p_h0, (void*)&p_h1, (void*)&p_esb,
                     (void*)&p_bar};
    hipLaunchCooperativeKernel((const void*)k_enc_pers, dim3(NBE), dim3(512), kargs, 0, stream);
  }

  // ---- esq = es @ Wq (for att = esq.h); av = es @ Wk^T + avtab ----
  k_bgemm<0, false, false><<<dim3(8, 128), blk, 0, stream>>>(
      esbf, 1024, WqTB, 1024, nullptr, esq, 1024, 1024, nullptr, nullptr, nullptr);
  k_bgemm<1, false, false><<<dim3(8, 128), blk, 0, stream>>>(
      esbf, 1024, WkB, 1024, nullptr, avbf, 1024, 1024, avtab, src_langs, src_chars);

  // ---- decoder: persistent cooperative kernel (init + 128 steps) ----
  {
    const unsigned short* p_whd = WhdB;
    const unsigned short* p_wic = WicB;
    const unsigned short* p_esq = esq;
    const unsigned short* p_av = avbf;
    const float* p_dgixt = dgixt;
    const int* p_tgt = tgt_chars;
    const float* p_bh = dec_bh;
    float* p_h = h;
    unsigned short* p_hbf = hbf;
    float* p_ctx = ctx;
    unsigned short* p_ctxbf = ctxbf;
    float* p_attL = attL;
    float* p_gh = ghbuf;
    unsigned short* p_hc = hcbf;
    int* p_bar = bar;
    void* kargs[] = {(void*)&p_whd, (void*)&p_wic, (void*)&p_esq, (void*)&p_av,
                     (void*)&p_dgixt, (void*)&p_tgt, (void*)&p_bh, (void*)&p_h,
                     (void*)&p_hbf, (void*)&p_ctx, (void*)&p_ctxbf, (void*)&p_attL,
                     (void*)&p_gh, (void*)&p_hc, (void*)&p_bar};
    hipLaunchCooperativeKernel((const void*)k_dec_pers, dim3(NBD), dim3(512), kargs, 0, stream);
  }

  // ---- MLP: scores = relu(relu(hc@W1^T+b1)@W2^T+b2)@W3^T ----
  k_bgemm<0, true, true><<<dim3(32, 32), blk, 0, stream>>>(
      hcbf, 1024, W1B, 1024, b1, G1, 4096, 1024, nullptr, nullptr, nullptr);
  k_bgemm<0, true, true><<<dim3(16, 32), blk, 0, stream>>>(
      G1, 4096, W2B, 4096, b2, G2, 2048, 4096, nullptr, nullptr, nullptr);
  k_bgemm<2, false, false><<<dim3(1, 32), blk, 0, stream>>>(
      G2, 2048, W3B, 2048, nullptr, out, 0, 2048, nullptr, nullptr, nullptr);
}

// Round 10
// 8573.867 us; speedup vs baseline: 1.4771x; 1.4771x over previous
//
#include <hip/hip_runtime.h>
#include <math.h>

// GRU enc-dec w/ attention. B=32,S=512,T=128,V=128,L=5,E=512,H=1024,F=2048.
// R12: revert to R7 (8790us proven: persistent encoder w/ flat RMW barrier +
//     LAUNCH-based decoder). Back-solve from R10: launch decoder = 4132us =
//     32us/step -- faster than every custom-barrier persistent variant
//     (R8 67, R10 35.5, R11 57.5 us/step). Software global barriers at >=128
//     blocks cost ~8-15us each; HW dispatch (~2us) wins. One change vs R7:
//     k_ctxsm w@av accumulation vectorized 2B -> 16B/lane (bf16x8, 16-s-group
//     fp32 regroup -- numerically validated in R10/R11, absmax unchanged).

#define Bb 32
#define Ss 512
#define Tt 128
#define Vv 128
#define Hh 1024
#define H3 3072
#define APAD 40
#define NBE 64   // persistent encoder blocks

typedef __attribute__((ext_vector_type(8))) short bf16x8;
typedef __attribute__((ext_vector_type(4))) float f32x4;

__device__ inline f32x4 mfma_bf16(bf16x8 a, bf16x8 b, f32x4 c) {
  return __builtin_amdgcn_mfma_f32_16x16x32_bf16(a, b, c, 0, 0, 0);
}
__device__ inline unsigned short f2bf(float f) {
  unsigned u = __builtin_bit_cast(unsigned, f);
  unsigned r = (u + 0x7fffu + ((u >> 16) & 1u)) >> 16;
  return (unsigned short)r;
}
__device__ inline float lof(unsigned u) { return __builtin_bit_cast(float, u << 16); }
__device__ inline float hif(unsigned u) { return __builtin_bit_cast(float, u & 0xffff0000u); }
__device__ inline float bf2f(unsigned short h) {
  return __builtin_bit_cast(float, ((unsigned)h) << 16);
}

// ---------------- workspace offsets (BYTES) ----------------
#define O_ESBF   0UL            // es bf16      [B*S][1024]  32MB
#define O_ESQ    33554432UL     // esq bf16     [B*S][1024]  32MB  (aliased: G1 in MLP)
#define O_AVBF   67108864UL     // av bf16      [B*S][1024]  32MB  (aliased: G2 in MLP)
#define O_HCBF   100663296UL    // hc bf16      [T*B][1024]   8MB
#define O_WHE    109051904UL    // enc_Wh bf16  [3072][1024]  6MB
#define O_WHD    115343360UL    // dec_Wh bf16  6MB
#define O_WIC    121634816UL    // dec_Wi ctx-cols bf16 [3072][1024] 6MB
#define O_WKB    127926272UL    // Wk bf16 [1024][1024] 2MB
#define O_WQT    130023424UL    // Wq^T bf16 [1024][1024] 2MB
#define O_W1B    132120576UL    // W1 bf16 [4096][1024] 8MB
#define O_W2B    140509184UL    // W2 bf16 [2048][4096] 16MB
#define O_W3B    157286400UL    // W3 bf16 [128][2048] 0.5MB
#define O_XCAT   157810688UL    // fp32 [640][1024]
#define O_EMBFC  160432128UL    // fp32 [640][512]
#define O_GITAB  161742848UL    // fp32 [640][3072]
#define O_AVTAB  169607168UL    // fp32 [640][1024]
#define O_DGIXT  172228608UL    // fp32 [128][3072]
#define O_GH     173801472UL    // fp32 [32][3072]
#define O_GI     174194688UL    // 384KB: cltab(64KB) + hbf2(64KB) + bar(128B)
#define O_H      174587904UL    // fp32 [32][1024]
#define O_HBF    174718976UL    // bf16 [32][1024]
#define O_CTX    174784512UL    // fp32 [32][1024]
#define O_CTXBF  174915584UL    // bf16 [32][1024]
#define O_ATTL   174981120UL    // fp32 [32][512]
// total ~167MB

// ---------------- setup helpers ----------------
__global__ void k_xcat(const float* __restrict__ ce, const float* __restrict__ le,
                       float* __restrict__ xcat) {
  int row = blockIdx.x;  // l*128 + c
  int l = row >> 7, c = row & 127;
  int i = threadIdx.x * 4;
  float4 v;
  if (i < 512) v = *(const float4*)(ce + c * 512 + i);
  else         v = *(const float4*)(le + l * 512 + (i - 512));
  *(float4*)(xcat + (size_t)row * 1024 + i) = v;
}

__global__ void k_cltab(const int* __restrict__ sc, const int* __restrict__ sl,
                        int* __restrict__ cl, int* __restrict__ bar) {
  if (blockIdx.x == 0 && threadIdx.x == 0) *bar = 0;  // enc barrier reset
  int i = blockIdx.x * 256 + threadIdx.x;  // 16384 = 32b * 512s
  int b = i >> 9, s = i & 511;
  cl[s * 32 + b] = sl[b * Ss + s] * 128 + sc[b * Ss + s];
}

__global__ void k_cvt(const float* __restrict__ src, int ld, int lc,
                      unsigned short* __restrict__ dst) {
  size_t i = ((size_t)blockIdx.x * 256 + threadIdx.x) * 8;
  size_t r = i >> lc;
  int c = (int)(i & ((1u << lc) - 1));
  const float* s = src + r * (size_t)ld + c;
  float4 v0 = *(const float4*)s;
  float4 v1 = *(const float4*)(s + 4);
  union { unsigned short us[8]; uint4 u; } o;
  o.us[0] = f2bf(v0.x); o.us[1] = f2bf(v0.y); o.us[2] = f2bf(v0.z); o.us[3] = f2bf(v0.w);
  o.us[4] = f2bf(v1.x); o.us[5] = f2bf(v1.y); o.us[6] = f2bf(v1.z); o.us[7] = f2bf(v1.w);
  *(uint4*)(dst + i) = o.u;
}

__global__ void k_transcvt(const float* __restrict__ in, unsigned short* __restrict__ out) {
  __shared__ float t[32][33];
  int c0 = blockIdx.x * 32, r0 = blockIdx.y * 32;
  int tx = threadIdx.x, ty = threadIdx.y;
  for (int i = ty; i < 32; i += 8)
    t[i][tx] = in[(size_t)(r0 + i) * 1024 + c0 + tx];
  __syncthreads();
  for (int i = ty; i < 32; i += 8)
    out[(size_t)(c0 + i) * 1024 + r0 + tx] = f2bf(t[tx][i]);
}

// ---------------- fp32 tiled GEMM (setup tables only): C=A@W^T ----------------
template <bool BIAS>
__global__ __launch_bounds__(256) void k_gemm(
    const float* __restrict__ A, int lda, const float* __restrict__ W, int ldw,
    const float* __restrict__ bias, float* __restrict__ C, int ldc, int K) {
  __shared__ float As[8][128];
  __shared__ float Ws[8][128];
  int tid = threadIdx.x;
  int n0 = blockIdx.x * 128, m0 = blockIdx.y * 128;
  int tx = tid & 15, ty = tid >> 4;
  int lrow = tid >> 1, lseg = (tid & 1) * 4;
  const float* Ap = A + (size_t)(m0 + lrow) * lda + lseg;
  const float* Wp = W + (size_t)(n0 + lrow) * ldw + lseg;
  float acc[8][8];
#pragma unroll
  for (int i = 0; i < 8; ++i)
#pragma unroll
    for (int j = 0; j < 8; ++j) acc[i][j] = 0.f;
  for (int kt = 0; kt < K; kt += 8) {
    float4 av = *(const float4*)(Ap + kt);
    float4 wv = *(const float4*)(Wp + kt);
    __syncthreads();
    As[lseg + 0][lrow] = av.x; As[lseg + 1][lrow] = av.y;
    As[lseg + 2][lrow] = av.z; As[lseg + 3][lrow] = av.w;
    Ws[lseg + 0][lrow] = wv.x; Ws[lseg + 1][lrow] = wv.y;
    Ws[lseg + 2][lrow] = wv.z; Ws[lseg + 3][lrow] = wv.w;
    __syncthreads();
#pragma unroll
    for (int kk = 0; kk < 8; ++kk) {
      float a[8], b[8];
      *(float4*)(a + 0) = *(const float4*)(&As[kk][ty * 8 + 0]);
      *(float4*)(a + 4) = *(const float4*)(&As[kk][ty * 8 + 4]);
      *(float4*)(b + 0) = *(const float4*)(&Ws[kk][tx * 8 + 0]);
      *(float4*)(b + 4) = *(const float4*)(&Ws[kk][tx * 8 + 4]);
#pragma unroll
      for (int i = 0; i < 8; ++i)
#pragma unroll
        for (int j = 0; j < 8; ++j) acc[i][j] = fmaf(a[i], b[j], acc[i][j]);
    }
  }
#pragma unroll
  for (int i = 0; i < 8; ++i) {
    int r = m0 + ty * 8 + i;
#pragma unroll
    for (int j = 0; j < 8; ++j) {
      int c = n0 + tx * 8 + j;
      float v = acc[i][j];
      if (BIAS) v += bias[c];
      C[(size_t)r * ldc + c] = v;
    }
  }
}

// ---------------- bf16 MFMA GEMM: C[M,N] = A[M,K] @ W[N,K]^T ----------------
// EPI: 0 store bf16; 1 +=avtab[lang*128+char][col], store bf16; 2 fp32 scatter to out
template <int EPI, bool RELU, bool BIAS>
__global__ __launch_bounds__(256) void k_bgemm(
    const unsigned short* __restrict__ A, int lda,
    const unsigned short* __restrict__ W, int ldw,
    const float* __restrict__ bias, void* __restrict__ Cout, int ldc, int K,
    const float* __restrict__ avtab, const int* __restrict__ gl,
    const int* __restrict__ gc) {
  __shared__ unsigned short As[128 * APAD];
  __shared__ unsigned short Bs[128 * APAD];
  int tid = threadIdx.x;
  int n0 = blockIdx.x * 128, m0 = blockIdx.y * 128;
  int w = tid >> 6, l = tid & 63;
  int mw = (w & 1) * 64, nw = (w >> 1) * 64;
  int lrow = tid >> 1, lk = (tid & 1) * 16;
  const unsigned short* Ap = A + (size_t)(m0 + lrow) * lda + lk;
  const unsigned short* Wp = W + (size_t)(n0 + lrow) * ldw + lk;
  int fr = l & 15, fk = (l >> 4) * 8;
  f32x4 acc[4][4];
#pragma unroll
  for (int i = 0; i < 4; ++i)
#pragma unroll
    for (int j = 0; j < 4; ++j) acc[i][j] = (f32x4){0.f, 0.f, 0.f, 0.f};
  for (int kt = 0; kt < K; kt += 32) {
    uint4 a0 = *(const uint4*)(Ap + kt);
    uint4 a1 = *(const uint4*)(Ap + kt + 8);
    uint4 b0 = *(const uint4*)(Wp + kt);
    uint4 b1 = *(const uint4*)(Wp + kt + 8);
    __syncthreads();
    *(uint4*)&As[lrow * APAD + lk] = a0;
    *(uint4*)&As[lrow * APAD + lk + 8] = a1;
    *(uint4*)&Bs[lrow * APAD + lk] = b0;
    *(uint4*)&Bs[lrow * APAD + lk + 8] = b1;
    __syncthreads();
    bf16x8 af[4], bfg[4];
#pragma unroll
    for (int i = 0; i < 4; ++i) af[i] = *(const bf16x8*)&As[(mw + i * 16 + fr) * APAD + fk];
#pragma unroll
    for (int j = 0; j < 4; ++j) bfg[j] = *(const bf16x8*)&Bs[(nw + j * 16 + fr) * APAD + fk];
#pragma unroll
    for (int i = 0; i < 4; ++i)
#pragma unroll
      for (int j = 0; j < 4; ++j) acc[i][j] = mfma_bf16(af[i], bfg[j], acc[i][j]);
  }
#pragma unroll
  for (int i = 0; i < 4; ++i)
#pragma unroll
    for (int j = 0; j < 4; ++j) {
      int col = n0 + nw + j * 16 + fr;
#pragma unroll
      for (int r = 0; r < 4; ++r) {
        int row = m0 + mw + i * 16 + (l >> 4) * 4 + r;
        float v = acc[i][j][r];
        if (BIAS) v += bias[col];
        if (RELU) v = fmaxf(v, 0.f);
        if (EPI == 0) {
          ((unsigned short*)Cout)[(size_t)row * ldc + col] = f2bf(v);
        } else if (EPI == 1) {
          int cl = gl[row] * 128 + gc[row];
          ((unsigned short*)Cout)[(size_t)row * ldc + col] =
              f2bf(v + avtab[(size_t)cl * 1024 + col]);
        } else {
          int tt = row >> 5, bb = row & 31;
          ((float*)Cout)[(size_t)bb * (Tt * Vv) + tt * Vv + col] = v;
        }
      }
    }
}

// ---------------- persistent encoder scan (R7, proven) ----------------
__global__ __launch_bounds__(512) void k_enc_pers(
    const unsigned short* __restrict__ Whe, const float* __restrict__ gitab,
    const int* __restrict__ cltab, const float* __restrict__ bh,
    float* __restrict__ h, unsigned short* __restrict__ hbf0,
    unsigned short* __restrict__ hbf1, unsigned short* __restrict__ esb,
    int* __restrict__ bar) {
  __shared__ unsigned short Ws[48 * 1024];  // 96KB
  __shared__ f32x4 red[8 * 6 * 64];         // 48KB
  int tid = threadIdx.x;
  int blk = blockIdx.x;
  int w = tid >> 6, l = tid & 63;
  int fr = l & 15, q = l >> 4;
  int j = blk * 16 + fr;
  {  // stage 48 Wh rows, XOR-swizzled per 16B chunk
    uint4* dst = (uint4*)Ws;
    const uint4* src = (const uint4*)Whe;
#pragma unroll
    for (int it = 0; it < 12; ++it) {
      int idx = it * 512 + tid;           // 0..6143
      int lr = idx >> 7, c = idx & 127;   // local row, chunk
      int grow = (lr >> 4) * 1024 + blk * 16 + (lr & 15);
      dst[lr * 128 + (c ^ (lr & 7))] = src[(size_t)grow * 128 + c];
    }
  }
  float bhr = bh[j], bhz = bh[1024 + j], bhn = bh[2048 + j];
  float hold[4] = {0.f, 0.f, 0.f, 0.f};
  __syncthreads();
  const bf16x8* Wsv = (const bf16x8*)Ws;
  int bc = 0;
  for (int s = 0; s < Ss; ++s) {
    unsigned short* wb = (s & 1) ? hbf1 : hbf0;
    const unsigned short* rb = (s & 1) ? hbf0 : hbf1;
    float gi0[4], gi1[4], gi2[4];
    if (w < 2) {
#pragma unroll
      for (int r = 0; r < 4; ++r) {
        int b = w * 16 + q * 4 + r;
        int c = cltab[s * 32 + b];
        const float* gp = gitab + (size_t)c * H3 + j;
        gi0[r] = gp[0]; gi1[r] = gp[1024]; gi2[r] = gp[2048];
      }
    }
    f32x4 acc[2][3];
#pragma unroll
    for (int m = 0; m < 2; ++m)
#pragma unroll
      for (int g = 0; g < 3; ++g) acc[m][g] = (f32x4){0.f, 0.f, 0.f, 0.f};
    if (s > 0) {
      int kb = w * 128 + q * 8;
      const unsigned short* A0 = rb + fr * 1024 + kb;
#pragma unroll
      for (int kt = 0; kt < 128; kt += 32) {
        bf16x8 a0 = *(const bf16x8*)(A0 + kt);
        bf16x8 a1 = *(const bf16x8*)(A0 + 16 * 1024 + kt);
        int c8 = (kb + kt) >> 3;
#pragma unroll
        for (int g = 0; g < 3; ++g) {
          bf16x8 bw = Wsv[(g * 16 + fr) * 128 + (c8 ^ (fr & 7))];
          acc[0][g] = mfma_bf16(a0, bw, acc[0][g]);
          acc[1][g] = mfma_bf16(a1, bw, acc[1][g]);
        }
      }
    }
#pragma unroll
    for (int m = 0; m < 2; ++m)
#pragma unroll
      for (int g = 0; g < 3; ++g)
        red[(w * 6 + m * 3 + g) * 64 + l] = acc[m][g];
    __syncthreads();
    if (w < 2) {
      int m = w;
      f32x4 as_[3];
#pragma unroll
      for (int g = 0; g < 3; ++g) as_[g] = (f32x4){0.f, 0.f, 0.f, 0.f};
#pragma unroll
      for (int ww = 0; ww < 8; ++ww)
#pragma unroll
        for (int g = 0; g < 3; ++g)
          as_[g] = as_[g] + red[(ww * 6 + m * 3 + g) * 64 + l];
#pragma unroll
      for (int r = 0; r < 4; ++r) {
        int b = m * 16 + q * 4 + r;
        float ghr = bhr + as_[0][r], ghz = bhz + as_[1][r], ghn = bhn + as_[2][r];
        float rg = 1.f / (1.f + expf(-(gi0[r] + ghr)));
        float zg = 1.f / (1.f + expf(-(gi1[r] + ghz)));
        float ng = tanhf(gi2[r] + rg * ghn);
        float hn = (1.f - zg) * ng + zg * hold[r];
        hold[r] = hn;
        unsigned short hb = f2bf(hn);
        wb[b * 1024 + j] = hb;
        esb[((size_t)b * Ss + s) * 1024 + j] = hb;
        if (s == Ss - 1) h[b * 1024 + j] = hn;
      }
    }
    __syncthreads();
    if (tid == 0) {
      __hip_atomic_fetch_add(bar, 1, __ATOMIC_RELEASE, __HIP_MEMORY_SCOPE_AGENT);
      ++bc;
      int tgt = NBE * bc;
      while (__hip_atomic_load(bar, __ATOMIC_RELAXED, __HIP_MEMORY_SCOPE_AGENT) < tgt)
        __builtin_amdgcn_s_sleep(1);
      __builtin_amdgcn_fence(__ATOMIC_ACQUIRE, "agent");
    }
    __syncthreads();
  }
}

// ---------------- fused recurrent step (split-K): MFMA + GRU gates ----------
// (decoder gi+gates) flags: bit0=hzero, bit1=usestart, bit2=skipMFMA.
template <int MODE>
__global__ __launch_bounds__(512) void k_step(
    const unsigned short* __restrict__ Wh,
    const unsigned short* __restrict__ Abf,
    const float* __restrict__ gtab,
    const int* __restrict__ idx,
    const float* __restrict__ ghb,
    const float* __restrict__ bh,
    float* __restrict__ h,
    unsigned short* __restrict__ hbfW,
    unsigned short* __restrict__ esb,
    int s, int flags) {
  __shared__ f32x4 red[8 * 6 * 64];  // 48KB
  int tid = threadIdx.x;
  int w = tid >> 6, l = tid & 63;
  int fr = l & 15, q = l >> 4;
  int j = blockIdx.x * 16 + fr;
  f32x4 acc[2][3];
#pragma unroll
  for (int m = 0; m < 2; ++m)
#pragma unroll
    for (int g = 0; g < 3; ++g) acc[m][g] = (f32x4){0.f, 0.f, 0.f, 0.f};
  if (!(flags & 4)) {
    int kb = w * 128 + q * 8;
    const unsigned short* A0 = Abf + fr * 1024 + kb;
    const unsigned short* W0 = Wh + (size_t)j * 1024 + kb;
#pragma unroll
    for (int kt = 0; kt < 128; kt += 32) {
      bf16x8 a0 = *(const bf16x8*)(A0 + kt);
      bf16x8 a1 = *(const bf16x8*)(A0 + 16 * 1024 + kt);
      bf16x8 b0 = *(const bf16x8*)(W0 + kt);
      bf16x8 b1 = *(const bf16x8*)(W0 + 1024 * 1024 + kt);
      bf16x8 b2 = *(const bf16x8*)(W0 + 2048 * 1024 + kt);
      acc[0][0] = mfma_bf16(a0, b0, acc[0][0]);
      acc[1][0] = mfma_bf16(a1, b0, acc[1][0]);
      acc[0][1] = mfma_bf16(a0, b1, acc[0][1]);
      acc[1][1] = mfma_bf16(a1, b1, acc[1][1]);
      acc[0][2] = mfma_bf16(a0, b2, acc[0][2]);
      acc[1][2] = mfma_bf16(a1, b2, acc[1][2]);
    }
  }
#pragma unroll
  for (int m = 0; m < 2; ++m)
#pragma unroll
    for (int g = 0; g < 3; ++g)
      red[(w * 6 + m * 3 + g) * 64 + l] = acc[m][g];
  __syncthreads();
  if (w >= 2) return;
  int m = w;  // wave 0 -> batch rows 0..15, wave 1 -> 16..31
  f32x4 as_[3];
#pragma unroll
  for (int g = 0; g < 3; ++g) as_[g] = (f32x4){0.f, 0.f, 0.f, 0.f};
#pragma unroll
  for (int ww = 0; ww < 8; ++ww)
#pragma unroll
    for (int g = 0; g < 3; ++g)
      as_[g] = as_[g] + red[(ww * 6 + m * 3 + g) * 64 + l];
  float bhr = bh[j], bhz = bh[1024 + j], bhn = bh[2048 + j];
#pragma unroll
  for (int r = 0; r < 4; ++r) {
    int b = m * 16 + q * 4 + r;
    int c = (MODE == 0) ? idx[s * 32 + b] : ((flags & 2) ? 1 : idx[b * Tt + s]);
    const float* gp = gtab + (size_t)c * H3 + j;
    float gir = gp[0], giz = gp[1024], gin = gp[2048];
    float ghr = bhr, ghz = bhz, ghn = bhn;
    if (MODE == 0) {
      ghr += as_[0][r]; ghz += as_[1][r]; ghn += as_[2][r];
    } else {
      gir += as_[0][r]; giz += as_[1][r]; gin += as_[2][r];
      if (!(flags & 1)) {
        const float* g2 = ghb + b * H3 + j;
        ghr += g2[0]; ghz += g2[1024]; ghn += g2[2048];
      }
    }
    float rg = 1.f / (1.f + expf(-(gir + ghr)));
    float zg = 1.f / (1.f + expf(-(giz + ghz)));
    float ng = tanhf(gin + rg * ghn);
    float hold = (flags & 1) ? 0.f : h[b * 1024 + j];
    float hn = (1.f - zg) * ng + zg * hold;
    h[b * 1024 + j] = hn;
    unsigned short hb = f2bf(hn);
    hbfW[b * 1024 + j] = hb;
    if (MODE == 0) esb[((size_t)b * Ss + s) * 1024 + j] = hb;
  }
}

// ---------------- M=32 recurrent MFMA GEMM (+ optional fused attention) ----------
// Blocks [0,nrec): C fp32 [32][N] = A_bf[32][1024] @ W_bf[N][1024]^T (64 cols/block)
// Blocks [nrec, nrec+256): att[b,s] = esq_bf[b,s,:].h[b,:] (+ hc-fold on first 4/b)
__global__ __launch_bounds__(256) void k_rec(
    const unsigned short* __restrict__ A, const unsigned short* __restrict__ W,
    float* __restrict__ C, int N, int nrec,
    const unsigned short* __restrict__ esq, const float* __restrict__ h,
    const float* __restrict__ ctx, float* __restrict__ attL,
    unsigned short* __restrict__ hc) {
  __shared__ unsigned short As[32 * 1024];  // 64KB; att branch reuses 4KB as fp32 h
  int tid = threadIdx.x;
  int id = blockIdx.x;
  if (id < nrec) {
    {
      const uint4* src = (const uint4*)A;
      uint4* dst = (uint4*)As;
#pragma unroll
      for (int i = 0; i < 16; ++i) {
        int c = i * 256 + tid;
        int m = c >> 7, kc = c & 127;
        dst[m * 128 + (kc ^ (m & 7))] = src[c];  // XOR-swizzle per 16B chunk
      }
    }
    __syncthreads();
    int w = tid >> 6, l = tid & 63;
    int nb = id * 64 + w * 16;
    int fr = l & 15, fk8 = (l >> 4);  // k-offset = fk8*8
    const unsigned short* Wp = W + (size_t)(nb + fr) * 1024 + fk8 * 8;
    const bf16x8* Asv = (const bf16x8*)As;
    f32x4 acc0 = (f32x4){0.f, 0.f, 0.f, 0.f}, acc1 = acc0;
#pragma unroll 8
    for (int kt = 0; kt < 1024; kt += 32) {
      int kc8 = (kt >> 3) + fk8;
      bf16x8 bw = *(const bf16x8*)(Wp + kt);
      bf16x8 a0 = Asv[fr * 128 + (kc8 ^ (fr & 7))];
      bf16x8 a1 = Asv[(fr + 16) * 128 + (kc8 ^ (fr & 7))];
      acc0 = mfma_bf16(a0, bw, acc0);
      acc1 = mfma_bf16(a1, bw, acc1);
    }
    int col = nb + fr;
    int rb = (l >> 4) * 4;
#pragma unroll
    for (int r = 0; r < 4; ++r) {
      C[(size_t)(rb + r) * N + col] = acc0[r];
      C[(size_t)(rb + r + 16) * N + col] = acc1[r];
    }
  } else {
    float* hs = (float*)As;
    int a = id - nrec, b = a >> 3, sc = a & 7;
    for (int i = tid; i < 1024; i += 256) hs[i] = h[b * 1024 + i];
    __syncthreads();
    if (sc < 4) {
      int j = sc * 256 + tid;
      hc[b * 1024 + j] = f2bf(hs[j] + ctx[b * 1024 + j]);
    }
    int sg = tid >> 2, li = tid & 3;
    int s = sc * 64 + sg;
    const unsigned short* ep = esq + (size_t)(b * 512 + s) * 1024;
    float acc = 0.f;
#pragma unroll 4
    for (int i = 0; i < 32; ++i) {
      int k = (i * 4 + li) * 8;
      uint4 e = *(const uint4*)(ep + k);
      float4 h0 = *(const float4*)&hs[k];
      float4 h1 = *(const float4*)&hs[k + 4];
      acc += lof(e.x) * h0.x + hif(e.x) * h0.y + lof(e.y) * h0.z + hif(e.y) * h0.w +
             lof(e.z) * h1.x + hif(e.z) * h1.y + lof(e.w) * h1.z + hif(e.w) * h1.w;
    }
    acc += __shfl_xor(acc, 1);
    acc += __shfl_xor(acc, 2);
    if (li == 0) attL[b * 512 + s] = acc;
  }
}

// ---------------- ctx init (ctx = final encoder h) ----------------
__global__ void k_ctxinit(const float* __restrict__ h, float* __restrict__ ctx,
                          unsigned short* __restrict__ ctxbf) {
  int idx = blockIdx.x * 256 + threadIdx.x;
  float v = h[idx];
  ctx[idx] = v;
  ctxbf[idx] = f2bf(v);
}

// ---------------- softmax + ctx = w @ av_bf (vectorized 16B/lane) ----------
// Softmax max/sum bit-identical to the original k_ctxsm; the ctx summation is
// regrouped into 16 s-groups x (16 lanes x 8 cols) with a fixed-order fp32
// LDS reduce (validated in R10/R11: absmax unchanged at 2.441e-4).
__global__ __launch_bounds__(256) void k_ctxsm(const float* __restrict__ attL,
                                               const unsigned short* __restrict__ av,
                                               float* __restrict__ ctx,
                                               unsigned short* __restrict__ ctxbf) {
  int jt = blockIdx.x, b = blockIdx.y;
  __shared__ float w[512];
  __shared__ float wm[4];
  __shared__ float wsm[4];
  __shared__ float scr[256 * 8];  // 8KB partials
  int tid = threadIdx.x;
  float a0 = attL[b * Ss + tid * 2];
  float a1 = attL[b * Ss + tid * 2 + 1];
  float m = fmaxf(a0, a1);
  for (int d = 1; d < 64; d <<= 1) m = fmaxf(m, __shfl_xor(m, d));
  if ((tid & 63) == 0) wm[tid >> 6] = m;
  __syncthreads();
  m = fmaxf(fmaxf(wm[0], wm[1]), fmaxf(wm[2], wm[3]));
  float e0 = expf(a0 - m), e1 = expf(a1 - m);
  w[tid * 2] = e0;
  w[tid * 2 + 1] = e1;
  float ssum = e0 + e1;
  for (int d = 1; d < 64; d <<= 1) ssum += __shfl_xor(ssum, d);
  if ((tid & 63) == 0) wsm[tid >> 6] = ssum;
  __syncthreads();
  float scale = 1.f / (wsm[0] + wsm[1] + wsm[2] + wsm[3]);
  int g = tid & 15, si = tid >> 4;  // 16 col-groups of 8 x 16 s-groups
  const unsigned short* avp = av + (size_t)(b * Ss) * Hh + jt * 128 + g * 8;
  float a8[8] = {0.f, 0.f, 0.f, 0.f, 0.f, 0.f, 0.f, 0.f};
#pragma unroll 4
  for (int s = si; s < 512; s += 16) {
    float wv = w[s];
    uint4 e = *(const uint4*)(avp + (size_t)s * Hh);
    a8[0] += wv * lof(e.x); a8[1] += wv * hif(e.x);
    a8[2] += wv * lof(e.y); a8[3] += wv * hif(e.y);
    a8[4] += wv * lof(e.z); a8[5] += wv * hif(e.z);
    a8[6] += wv * lof(e.w); a8[7] += wv * hif(e.w);
  }
#pragma unroll
  for (int k2 = 0; k2 < 8; ++k2) scr[tid * 8 + k2] = a8[k2];
  __syncthreads();
  if (tid < 128) {
    int g2 = tid >> 3, k2 = tid & 7;
    float p = 0.f;
#pragma unroll
    for (int si2 = 0; si2 < 16; ++si2) p += scr[(si2 * 16 + g2) * 8 + k2];
    float v = p * scale;
    int j3 = b * Hh + jt * 128 + tid;
    ctx[j3] = v;
    ctxbf[j3] = f2bf(v);
  }
}

// ---------------- host ----------------
extern "C" void kernel_launch(void* const* d_in, const int* in_sizes, int n_in,
                              void* d_out, int out_size, void* d_ws, size_t ws_size,
                              hipStream_t stream) {
  (void)in_sizes; (void)n_in; (void)out_size; (void)ws_size;
  const int*   src_chars = (const int*)d_in[0];
  const int*   src_langs = (const int*)d_in[1];
  const int*   tgt_chars = (const int*)d_in[2];
  const float* char_emb  = (const float*)d_in[3];
  const float* lang_emb  = (const float*)d_in[4];
  const float* fc_W  = (const float*)d_in[5];
  const float* fc_b  = (const float*)d_in[6];
  const float* enc_Wi = (const float*)d_in[7];
  const float* enc_Wh = (const float*)d_in[8];
  const float* enc_bi = (const float*)d_in[9];
  const float* enc_bh = (const float*)d_in[10];
  const float* dec_Wi = (const float*)d_in[11];
  const float* dec_Wh = (const float*)d_in[12];
  const float* dec_bi = (const float*)d_in[13];
  const float* dec_bh = (const float*)d_in[14];
  const float* Wq  = (const float*)d_in[15];
  const float* Wk  = (const float*)d_in[16];
  const float* Wcs = (const float*)d_in[17];
  const float* W1 = (const float*)d_in[18];
  const float* b1 = (const float*)d_in[19];
  const float* W2 = (const float*)d_in[20];
  const float* b2 = (const float*)d_in[21];
  const float* W3 = (const float*)d_in[22];
  float* out = (float*)d_out;

  char* ws = (char*)d_ws;
  unsigned short* esbf  = (unsigned short*)(ws + O_ESBF);
  unsigned short* esq   = (unsigned short*)(ws + O_ESQ);
  unsigned short* avbf  = (unsigned short*)(ws + O_AVBF);
  unsigned short* hcbf  = (unsigned short*)(ws + O_HCBF);
  unsigned short* WheB  = (unsigned short*)(ws + O_WHE);
  unsigned short* WhdB  = (unsigned short*)(ws + O_WHD);
  unsigned short* WicB  = (unsigned short*)(ws + O_WIC);
  unsigned short* WkB   = (unsigned short*)(ws + O_WKB);
  unsigned short* WqTB  = (unsigned short*)(ws + O_WQT);
  unsigned short* W1B   = (unsigned short*)(ws + O_W1B);
  unsigned short* W2B   = (unsigned short*)(ws + O_W2B);
  unsigned short* W3B   = (unsigned short*)(ws + O_W3B);
  float* xcat   = (float*)(ws + O_XCAT);
  float* embfc  = (float*)(ws + O_EMBFC);
  float* gitab  = (float*)(ws + O_GITAB);
  float* avtab  = (float*)(ws + O_AVTAB);
  float* dgixt  = (float*)(ws + O_DGIXT);
  float* ghbuf  = (float*)(ws + O_GH);
  float* h      = (float*)(ws + O_H);
  unsigned short* hbf   = (unsigned short*)(ws + O_HBF);
  float* ctx    = (float*)(ws + O_CTX);
  unsigned short* ctxbf = (unsigned short*)(ws + O_CTXBF);
  float* attL   = (float*)(ws + O_ATTL);
  unsigned short* G1 = esq;   // alias: dead after decoder
  unsigned short* G2 = avbf;  // alias: dead after decoder
  int* cltab = (int*)(ws + O_GI);                               // 64KB
  unsigned short* hbf2 = (unsigned short*)(ws + O_GI + 65536);  // 64KB enc dbuf
  int* bar = (int*)(ws + O_GI + 131072);                        // enc barrier

  dim3 blk(256);

  // ---- tables (fp32) ----
  k_xcat<<<640, blk, 0, stream>>>(char_emb, lang_emb, xcat);
  k_cltab<<<64, blk, 0, stream>>>(src_chars, src_langs, cltab, bar);
  k_gemm<true><<<dim3(4, 5), blk, 0, stream>>>(xcat, 1024, fc_W, 1024, fc_b, embfc, 512, 1024);
  k_gemm<true><<<dim3(24, 5), blk, 0, stream>>>(embfc, 512, enc_Wi, 512, enc_bi, gitab, H3, 512);
  k_gemm<false><<<dim3(8, 5), blk, 0, stream>>>(embfc, 512, Wcs, 512, nullptr, avtab, Hh, 512);
  k_gemm<true><<<dim3(24, 1), blk, 0, stream>>>(embfc + 512 * 512, 512, dec_Wi, 1536, dec_bi,
                                                dgixt, H3, 512);
  // ---- weight conversions ----
  k_cvt<<<1536, blk, 0, stream>>>(enc_Wh, 1024, 10, WheB);
  k_cvt<<<1536, blk, 0, stream>>>(dec_Wh, 1024, 10, WhdB);
  k_cvt<<<1536, blk, 0, stream>>>(dec_Wi + 512, 1536, 10, WicB);
  k_cvt<<<512,  blk, 0, stream>>>(Wk, 1024, 10, WkB);
  k_cvt<<<2048, blk, 0, stream>>>(W1, 1024, 10, W1B);
  k_cvt<<<4096, blk, 0, stream>>>(W2, 4096, 12, W2B);
  k_cvt<<<128,  blk, 0, stream>>>(W3, 2048, 11, W3B);
  k_transcvt<<<dim3(32, 32), dim3(32, 8), 0, stream>>>(Wq, WqTB);

  // ---- encoder scan: persistent cooperative kernel, custom barrier ----
  {
    const unsigned short* p_whe = WheB;
    const float* p_git = gitab;
    const int* p_cl = cltab;
    const float* p_bh = enc_bh;
    float* p_h = h;
    unsigned short* p_h0 = hbf;   // s even writes hbf (R6 parity)
    unsigned short* p_h1 = hbf2;
    unsigned short* p_esb = esbf;
    int* p_bar = bar;
    void* kargs[] = {(void*)&p_whe, (void*)&p_git, (void*)&p_cl, (void*)&p_bh,
                     (void*)&p_h, (void*)&p_h0, (void*)&p_h1, (void*)&p_esb,
                     (void*)&p_bar};
    hipLaunchCooperativeKernel((const void*)k_enc_pers, dim3(NBE), dim3(512), kargs, 0, stream);
  }

  // ---- esq = es @ Wq (for att = esq.h); av = es @ Wk^T + avtab ----
  k_bgemm<0, false, false><<<dim3(8, 128), blk, 0, stream>>>(
      esbf, 1024, WqTB, 1024, nullptr, esq, 1024, 1024, nullptr, nullptr, nullptr);
  k_bgemm<1, false, false><<<dim3(8, 128), blk, 0, stream>>>(
      esbf, 1024, WkB, 1024, nullptr, avbf, 1024, 1024, avtab, src_langs, src_chars);

  // ---- decoder init: h0 = gru(0, [start_emb, ctx0]) ----
  k_ctxinit<<<128, blk, 0, stream>>>(h, ctx, ctxbf);
  k_step<1><<<64, 512, 0, stream>>>(WicB, ctxbf, dgixt, tgt_chars, nullptr, dec_bh,
                                    h, hbf, nullptr, 0, 3);

  // ---- decoder scan: [gh + att + hc] / ctxsm / [gi + gates] ----
  for (int t = 0; t < Tt; ++t) {
    k_rec<<<304, blk, 0, stream>>>(hbf, WhdB, ghbuf, H3, 48,
                                   esq, h, ctx, attL, hcbf + (size_t)t * Bb * Hh);
    if (t == Tt - 1) break;
    k_ctxsm<<<dim3(8, 32), blk, 0, stream>>>(attL, avbf, ctx, ctxbf);
    k_step<1><<<64, 512, 0, stream>>>(WicB, ctxbf, dgixt, tgt_chars, ghbuf, dec_bh,
                                      h, hbf, nullptr, t, 0);
  }

  // ---- MLP: scores = relu(relu(hc@W1^T+b1)@W2^T+b2)@W3^T ----
  k_bgemm<0, true, true><<<dim3(32, 32), blk, 0, stream>>>(
      hcbf, 1024, W1B, 1024, b1, G1, 4096, 1024, nullptr, nullptr, nullptr);
  k_bgemm<0, true, true><<<dim3(16, 32), blk, 0, stream>>>(
      G1, 4096, W2B, 4096, b2, G2, 2048, 4096, nullptr, nullptr, nullptr);
  k_bgemm<2, false, false><<<dim3(1, 32), blk, 0, stream>>>(
      G2, 2048, W3B, 2048, nullptr, out, 0, 2048, nullptr, nullptr, nullptr);
}

// Round 11
// 8519.075 us; speedup vs baseline: 1.4866x; 1.0064x over previous
//
#include <hip/hip_runtime.h>
#include <math.h>

// GRU enc-dec w/ attention. B=32,S=512,T=128,V=128,L=5,E=512,H=1024,F=2048.
// R13: decoder stream-concurrency tuning on the R12 base (8574us best):
//     (1) k_ctxsm 256->512 blocks (64-col slices, 16 s-iters/thread, ctx
//         partials regrouped 16->32 s-groups, fp32 fixed order);
//     (2) k_rec att stream unroll 4->8 (order unchanged, attL bit-identical);
//     (3) k_step 64->128 blocks via batch-half (m) split -- each K-chain and
//         reduce order bit-identical; 2x CU coverage.
//     Encoder (persistent, flat RMW barrier) untouched.

#define Bb 32
#define Ss 512
#define Tt 128
#define Vv 128
#define Hh 1024
#define H3 3072
#define APAD 40
#define NBE 64   // persistent encoder blocks

typedef __attribute__((ext_vector_type(8))) short bf16x8;
typedef __attribute__((ext_vector_type(4))) float f32x4;

__device__ inline f32x4 mfma_bf16(bf16x8 a, bf16x8 b, f32x4 c) {
  return __builtin_amdgcn_mfma_f32_16x16x32_bf16(a, b, c, 0, 0, 0);
}
__device__ inline unsigned short f2bf(float f) {
  unsigned u = __builtin_bit_cast(unsigned, f);
  unsigned r = (u + 0x7fffu + ((u >> 16) & 1u)) >> 16;
  return (unsigned short)r;
}
__device__ inline float lof(unsigned u) { return __builtin_bit_cast(float, u << 16); }
__device__ inline float hif(unsigned u) { return __builtin_bit_cast(float, u & 0xffff0000u); }
__device__ inline float bf2f(unsigned short h) {
  return __builtin_bit_cast(float, ((unsigned)h) << 16);
}

// ---------------- workspace offsets (BYTES) ----------------
#define O_ESBF   0UL            // es bf16      [B*S][1024]  32MB
#define O_ESQ    33554432UL     // esq bf16     [B*S][1024]  32MB  (aliased: G1 in MLP)
#define O_AVBF   67108864UL     // av bf16      [B*S][1024]  32MB  (aliased: G2 in MLP)
#define O_HCBF   100663296UL    // hc bf16      [T*B][1024]   8MB
#define O_WHE    109051904UL    // enc_Wh bf16  [3072][1024]  6MB
#define O_WHD    115343360UL    // dec_Wh bf16  6MB
#define O_WIC    121634816UL    // dec_Wi ctx-cols bf16 [3072][1024] 6MB
#define O_WKB    127926272UL    // Wk bf16 [1024][1024] 2MB
#define O_WQT    130023424UL    // Wq^T bf16 [1024][1024] 2MB
#define O_W1B    132120576UL    // W1 bf16 [4096][1024] 8MB
#define O_W2B    140509184UL    // W2 bf16 [2048][4096] 16MB
#define O_W3B    157286400UL    // W3 bf16 [128][2048] 0.5MB
#define O_XCAT   157810688UL    // fp32 [640][1024]
#define O_EMBFC  160432128UL    // fp32 [640][512]
#define O_GITAB  161742848UL    // fp32 [640][3072]
#define O_AVTAB  169607168UL    // fp32 [640][1024]
#define O_DGIXT  172228608UL    // fp32 [128][3072]
#define O_GH     173801472UL    // fp32 [32][3072]
#define O_GI     174194688UL    // 384KB: cltab(64KB) + hbf2(64KB) + bar(128B)
#define O_H      174587904UL    // fp32 [32][1024]
#define O_HBF    174718976UL    // bf16 [32][1024]
#define O_CTX    174784512UL    // fp32 [32][1024]
#define O_CTXBF  174915584UL    // bf16 [32][1024]
#define O_ATTL   174981120UL    // fp32 [32][512]
// total ~167MB

// ---------------- setup helpers ----------------
__global__ void k_xcat(const float* __restrict__ ce, const float* __restrict__ le,
                       float* __restrict__ xcat) {
  int row = blockIdx.x;  // l*128 + c
  int l = row >> 7, c = row & 127;
  int i = threadIdx.x * 4;
  float4 v;
  if (i < 512) v = *(const float4*)(ce + c * 512 + i);
  else         v = *(const float4*)(le + l * 512 + (i - 512));
  *(float4*)(xcat + (size_t)row * 1024 + i) = v;
}

__global__ void k_cltab(const int* __restrict__ sc, const int* __restrict__ sl,
                        int* __restrict__ cl, int* __restrict__ bar) {
  if (blockIdx.x == 0 && threadIdx.x == 0) *bar = 0;  // enc barrier reset
  int i = blockIdx.x * 256 + threadIdx.x;  // 16384 = 32b * 512s
  int b = i >> 9, s = i & 511;
  cl[s * 32 + b] = sl[b * Ss + s] * 128 + sc[b * Ss + s];
}

__global__ void k_cvt(const float* __restrict__ src, int ld, int lc,
                      unsigned short* __restrict__ dst) {
  size_t i = ((size_t)blockIdx.x * 256 + threadIdx.x) * 8;
  size_t r = i >> lc;
  int c = (int)(i & ((1u << lc) - 1));
  const float* s = src + r * (size_t)ld + c;
  float4 v0 = *(const float4*)s;
  float4 v1 = *(const float4*)(s + 4);
  union { unsigned short us[8]; uint4 u; } o;
  o.us[0] = f2bf(v0.x); o.us[1] = f2bf(v0.y); o.us[2] = f2bf(v0.z); o.us[3] = f2bf(v0.w);
  o.us[4] = f2bf(v1.x); o.us[5] = f2bf(v1.y); o.us[6] = f2bf(v1.z); o.us[7] = f2bf(v1.w);
  *(uint4*)(dst + i) = o.u;
}

__global__ void k_transcvt(const float* __restrict__ in, unsigned short* __restrict__ out) {
  __shared__ float t[32][33];
  int c0 = blockIdx.x * 32, r0 = blockIdx.y * 32;
  int tx = threadIdx.x, ty = threadIdx.y;
  for (int i = ty; i < 32; i += 8)
    t[i][tx] = in[(size_t)(r0 + i) * 1024 + c0 + tx];
  __syncthreads();
  for (int i = ty; i < 32; i += 8)
    out[(size_t)(c0 + i) * 1024 + r0 + tx] = f2bf(t[tx][i]);
}

// ---------------- fp32 tiled GEMM (setup tables only): C=A@W^T ----------------
template <bool BIAS>
__global__ __launch_bounds__(256) void k_gemm(
    const float* __restrict__ A, int lda, const float* __restrict__ W, int ldw,
    const float* __restrict__ bias, float* __restrict__ C, int ldc, int K) {
  __shared__ float As[8][128];
  __shared__ float Ws[8][128];
  int tid = threadIdx.x;
  int n0 = blockIdx.x * 128, m0 = blockIdx.y * 128;
  int tx = tid & 15, ty = tid >> 4;
  int lrow = tid >> 1, lseg = (tid & 1) * 4;
  const float* Ap = A + (size_t)(m0 + lrow) * lda + lseg;
  const float* Wp = W + (size_t)(n0 + lrow) * ldw + lseg;
  float acc[8][8];
#pragma unroll
  for (int i = 0; i < 8; ++i)
#pragma unroll
    for (int j = 0; j < 8; ++j) acc[i][j] = 0.f;
  for (int kt = 0; kt < K; kt += 8) {
    float4 av = *(const float4*)(Ap + kt);
    float4 wv = *(const float4*)(Wp + kt);
    __syncthreads();
    As[lseg + 0][lrow] = av.x; As[lseg + 1][lrow] = av.y;
    As[lseg + 2][lrow] = av.z; As[lseg + 3][lrow] = av.w;
    Ws[lseg + 0][lrow] = wv.x; Ws[lseg + 1][lrow] = wv.y;
    Ws[lseg + 2][lrow] = wv.z; Ws[lseg + 3][lrow] = wv.w;
    __syncthreads();
#pragma unroll
    for (int kk = 0; kk < 8; ++kk) {
      float a[8], b[8];
      *(float4*)(a + 0) = *(const float4*)(&As[kk][ty * 8 + 0]);
      *(float4*)(a + 4) = *(const float4*)(&As[kk][ty * 8 + 4]);
      *(float4*)(b + 0) = *(const float4*)(&Ws[kk][tx * 8 + 0]);
      *(float4*)(b + 4) = *(const float4*)(&Ws[kk][tx * 8 + 4]);
#pragma unroll
      for (int i = 0; i < 8; ++i)
#pragma unroll
        for (int j = 0; j < 8; ++j) acc[i][j] = fmaf(a[i], b[j], acc[i][j]);
    }
  }
#pragma unroll
  for (int i = 0; i < 8; ++i) {
    int r = m0 + ty * 8 + i;
#pragma unroll
    for (int j = 0; j < 8; ++j) {
      int c = n0 + tx * 8 + j;
      float v = acc[i][j];
      if (BIAS) v += bias[c];
      C[(size_t)r * ldc + c] = v;
    }
  }
}

// ---------------- bf16 MFMA GEMM: C[M,N] = A[M,K] @ W[N,K]^T ----------------
// EPI: 0 store bf16; 1 +=avtab[lang*128+char][col], store bf16; 2 fp32 scatter to out
template <int EPI, bool RELU, bool BIAS>
__global__ __launch_bounds__(256) void k_bgemm(
    const unsigned short* __restrict__ A, int lda,
    const unsigned short* __restrict__ W, int ldw,
    const float* __restrict__ bias, void* __restrict__ Cout, int ldc, int K,
    const float* __restrict__ avtab, const int* __restrict__ gl,
    const int* __restrict__ gc) {
  __shared__ unsigned short As[128 * APAD];
  __shared__ unsigned short Bs[128 * APAD];
  int tid = threadIdx.x;
  int n0 = blockIdx.x * 128, m0 = blockIdx.y * 128;
  int w = tid >> 6, l = tid & 63;
  int mw = (w & 1) * 64, nw = (w >> 1) * 64;
  int lrow = tid >> 1, lk = (tid & 1) * 16;
  const unsigned short* Ap = A + (size_t)(m0 + lrow) * lda + lk;
  const unsigned short* Wp = W + (size_t)(n0 + lrow) * ldw + lk;
  int fr = l & 15, fk = (l >> 4) * 8;
  f32x4 acc[4][4];
#pragma unroll
  for (int i = 0; i < 4; ++i)
#pragma unroll
    for (int j = 0; j < 4; ++j) acc[i][j] = (f32x4){0.f, 0.f, 0.f, 0.f};
  for (int kt = 0; kt < K; kt += 32) {
    uint4 a0 = *(const uint4*)(Ap + kt);
    uint4 a1 = *(const uint4*)(Ap + kt + 8);
    uint4 b0 = *(const uint4*)(Wp + kt);
    uint4 b1 = *(const uint4*)(Wp + kt + 8);
    __syncthreads();
    *(uint4*)&As[lrow * APAD + lk] = a0;
    *(uint4*)&As[lrow * APAD + lk + 8] = a1;
    *(uint4*)&Bs[lrow * APAD + lk] = b0;
    *(uint4*)&Bs[lrow * APAD + lk + 8] = b1;
    __syncthreads();
    bf16x8 af[4], bfg[4];
#pragma unroll
    for (int i = 0; i < 4; ++i) af[i] = *(const bf16x8*)&As[(mw + i * 16 + fr) * APAD + fk];
#pragma unroll
    for (int j = 0; j < 4; ++j) bfg[j] = *(const bf16x8*)&Bs[(nw + j * 16 + fr) * APAD + fk];
#pragma unroll
    for (int i = 0; i < 4; ++i)
#pragma unroll
      for (int j = 0; j < 4; ++j) acc[i][j] = mfma_bf16(af[i], bfg[j], acc[i][j]);
  }
#pragma unroll
  for (int i = 0; i < 4; ++i)
#pragma unroll
    for (int j = 0; j < 4; ++j) {
      int col = n0 + nw + j * 16 + fr;
#pragma unroll
      for (int r = 0; r < 4; ++r) {
        int row = m0 + mw + i * 16 + (l >> 4) * 4 + r;
        float v = acc[i][j][r];
        if (BIAS) v += bias[col];
        if (RELU) v = fmaxf(v, 0.f);
        if (EPI == 0) {
          ((unsigned short*)Cout)[(size_t)row * ldc + col] = f2bf(v);
        } else if (EPI == 1) {
          int cl = gl[row] * 128 + gc[row];
          ((unsigned short*)Cout)[(size_t)row * ldc + col] =
              f2bf(v + avtab[(size_t)cl * 1024 + col]);
        } else {
          int tt = row >> 5, bb = row & 31;
          ((float*)Cout)[(size_t)bb * (Tt * Vv) + tt * Vv + col] = v;
        }
      }
    }
}

// ---------------- persistent encoder scan (R7, proven) ----------------
__global__ __launch_bounds__(512) void k_enc_pers(
    const unsigned short* __restrict__ Whe, const float* __restrict__ gitab,
    const int* __restrict__ cltab, const float* __restrict__ bh,
    float* __restrict__ h, unsigned short* __restrict__ hbf0,
    unsigned short* __restrict__ hbf1, unsigned short* __restrict__ esb,
    int* __restrict__ bar) {
  __shared__ unsigned short Ws[48 * 1024];  // 96KB
  __shared__ f32x4 red[8 * 6 * 64];         // 48KB
  int tid = threadIdx.x;
  int blk = blockIdx.x;
  int w = tid >> 6, l = tid & 63;
  int fr = l & 15, q = l >> 4;
  int j = blk * 16 + fr;
  {  // stage 48 Wh rows, XOR-swizzled per 16B chunk
    uint4* dst = (uint4*)Ws;
    const uint4* src = (const uint4*)Whe;
#pragma unroll
    for (int it = 0; it < 12; ++it) {
      int idx = it * 512 + tid;           // 0..6143
      int lr = idx >> 7, c = idx & 127;   // local row, chunk
      int grow = (lr >> 4) * 1024 + blk * 16 + (lr & 15);
      dst[lr * 128 + (c ^ (lr & 7))] = src[(size_t)grow * 128 + c];
    }
  }
  float bhr = bh[j], bhz = bh[1024 + j], bhn = bh[2048 + j];
  float hold[4] = {0.f, 0.f, 0.f, 0.f};
  __syncthreads();
  const bf16x8* Wsv = (const bf16x8*)Ws;
  int bc = 0;
  for (int s = 0; s < Ss; ++s) {
    unsigned short* wb = (s & 1) ? hbf1 : hbf0;
    const unsigned short* rb = (s & 1) ? hbf0 : hbf1;
    float gi0[4], gi1[4], gi2[4];
    if (w < 2) {
#pragma unroll
      for (int r = 0; r < 4; ++r) {
        int b = w * 16 + q * 4 + r;
        int c = cltab[s * 32 + b];
        const float* gp = gitab + (size_t)c * H3 + j;
        gi0[r] = gp[0]; gi1[r] = gp[1024]; gi2[r] = gp[2048];
      }
    }
    f32x4 acc[2][3];
#pragma unroll
    for (int m = 0; m < 2; ++m)
#pragma unroll
      for (int g = 0; g < 3; ++g) acc[m][g] = (f32x4){0.f, 0.f, 0.f, 0.f};
    if (s > 0) {
      int kb = w * 128 + q * 8;
      const unsigned short* A0 = rb + fr * 1024 + kb;
#pragma unroll
      for (int kt = 0; kt < 128; kt += 32) {
        bf16x8 a0 = *(const bf16x8*)(A0 + kt);
        bf16x8 a1 = *(const bf16x8*)(A0 + 16 * 1024 + kt);
        int c8 = (kb + kt) >> 3;
#pragma unroll
        for (int g = 0; g < 3; ++g) {
          bf16x8 bw = Wsv[(g * 16 + fr) * 128 + (c8 ^ (fr & 7))];
          acc[0][g] = mfma_bf16(a0, bw, acc[0][g]);
          acc[1][g] = mfma_bf16(a1, bw, acc[1][g]);
        }
      }
    }
#pragma unroll
    for (int m = 0; m < 2; ++m)
#pragma unroll
      for (int g = 0; g < 3; ++g)
        red[(w * 6 + m * 3 + g) * 64 + l] = acc[m][g];
    __syncthreads();
    if (w < 2) {
      int m = w;
      f32x4 as_[3];
#pragma unroll
      for (int g = 0; g < 3; ++g) as_[g] = (f32x4){0.f, 0.f, 0.f, 0.f};
#pragma unroll
      for (int ww = 0; ww < 8; ++ww)
#pragma unroll
        for (int g = 0; g < 3; ++g)
          as_[g] = as_[g] + red[(ww * 6 + m * 3 + g) * 64 + l];
#pragma unroll
      for (int r = 0; r < 4; ++r) {
        int b = m * 16 + q * 4 + r;
        float ghr = bhr + as_[0][r], ghz = bhz + as_[1][r], ghn = bhn + as_[2][r];
        float rg = 1.f / (1.f + expf(-(gi0[r] + ghr)));
        float zg = 1.f / (1.f + expf(-(gi1[r] + ghz)));
        float ng = tanhf(gi2[r] + rg * ghn);
        float hn = (1.f - zg) * ng + zg * hold[r];
        hold[r] = hn;
        unsigned short hb = f2bf(hn);
        wb[b * 1024 + j] = hb;
        esb[((size_t)b * Ss + s) * 1024 + j] = hb;
        if (s == Ss - 1) h[b * 1024 + j] = hn;
      }
    }
    __syncthreads();
    if (tid == 0) {
      __hip_atomic_fetch_add(bar, 1, __ATOMIC_RELEASE, __HIP_MEMORY_SCOPE_AGENT);
      ++bc;
      int tgt = NBE * bc;
      while (__hip_atomic_load(bar, __ATOMIC_RELAXED, __HIP_MEMORY_SCOPE_AGENT) < tgt)
        __builtin_amdgcn_s_sleep(1);
      __builtin_amdgcn_fence(__ATOMIC_ACQUIRE, "agent");
    }
    __syncthreads();
  }
}

// ---------------- fused recurrent step (split-K + m-split): MFMA + gates ----
// 128 blocks x 512 thr: block = (mb = blk>>6, 16-col slice jsl = (blk&63)*16).
// Each block computes the batch-half mb only; the 8-wave K-split chain and the
// ww-ordered reduce are bit-identical to the 64-block version (per-m chains
// were already independent). flags: bit0=hzero, bit1=usestart, bit2=skipMFMA.
template <int MODE>
__global__ __launch_bounds__(512) void k_step(
    const unsigned short* __restrict__ Wh,
    const unsigned short* __restrict__ Abf,
    const float* __restrict__ gtab,
    const int* __restrict__ idx,
    const float* __restrict__ ghb,
    const float* __restrict__ bh,
    float* __restrict__ h,
    unsigned short* __restrict__ hbfW,
    unsigned short* __restrict__ esb,
    int s, int flags) {
  __shared__ f32x4 red[8 * 3 * 64];  // 24KB
  int tid = threadIdx.x;
  int w = tid >> 6, l = tid & 63;
  int fr = l & 15, q = l >> 4;
  int mb = blockIdx.x >> 6;
  int j = (blockIdx.x & 63) * 16 + fr;
  f32x4 acc[3];
#pragma unroll
  for (int g = 0; g < 3; ++g) acc[g] = (f32x4){0.f, 0.f, 0.f, 0.f};
  if (!(flags & 4)) {
    int kb = w * 128 + q * 8;
    const unsigned short* A0 = Abf + (fr + mb * 16) * 1024 + kb;
    const unsigned short* W0 = Wh + (size_t)j * 1024 + kb;
#pragma unroll
    for (int kt = 0; kt < 128; kt += 32) {
      bf16x8 a0 = *(const bf16x8*)(A0 + kt);
      bf16x8 b0 = *(const bf16x8*)(W0 + kt);
      bf16x8 b1 = *(const bf16x8*)(W0 + 1024 * 1024 + kt);
      bf16x8 b2 = *(const bf16x8*)(W0 + 2048 * 1024 + kt);
      acc[0] = mfma_bf16(a0, b0, acc[0]);
      acc[1] = mfma_bf16(a0, b1, acc[1]);
      acc[2] = mfma_bf16(a0, b2, acc[2]);
    }
  }
#pragma unroll
  for (int g = 0; g < 3; ++g)
    red[(w * 3 + g) * 64 + l] = acc[g];
  __syncthreads();
  if (w >= 1) return;
  f32x4 as_[3];
#pragma unroll
  for (int g = 0; g < 3; ++g) as_[g] = (f32x4){0.f, 0.f, 0.f, 0.f};
#pragma unroll
  for (int ww = 0; ww < 8; ++ww)
#pragma unroll
    for (int g = 0; g < 3; ++g)
      as_[g] = as_[g] + red[(ww * 3 + g) * 64 + l];
  float bhr = bh[j], bhz = bh[1024 + j], bhn = bh[2048 + j];
#pragma unroll
  for (int r = 0; r < 4; ++r) {
    int b = mb * 16 + q * 4 + r;
    int c = (MODE == 0) ? idx[s * 32 + b] : ((flags & 2) ? 1 : idx[b * Tt + s]);
    const float* gp = gtab + (size_t)c * H3 + j;
    float gir = gp[0], giz = gp[1024], gin = gp[2048];
    float ghr = bhr, ghz = bhz, ghn = bhn;
    if (MODE == 0) {
      ghr += as_[0][r]; ghz += as_[1][r]; ghn += as_[2][r];
    } else {
      gir += as_[0][r]; giz += as_[1][r]; gin += as_[2][r];
      if (!(flags & 1)) {
        const float* g2 = ghb + b * H3 + j;
        ghr += g2[0]; ghz += g2[1024]; ghn += g2[2048];
      }
    }
    float rg = 1.f / (1.f + expf(-(gir + ghr)));
    float zg = 1.f / (1.f + expf(-(giz + ghz)));
    float ng = tanhf(gin + rg * ghn);
    float hold = (flags & 1) ? 0.f : h[b * 1024 + j];
    float hn = (1.f - zg) * ng + zg * hold;
    h[b * 1024 + j] = hn;
    unsigned short hb = f2bf(hn);
    hbfW[b * 1024 + j] = hb;
    if (MODE == 0) esb[((size_t)b * Ss + s) * 1024 + j] = hb;
  }
}

// ---------------- M=32 recurrent MFMA GEMM (+ optional fused attention) ----------
// Blocks [0,nrec): C fp32 [32][N] = A_bf[32][1024] @ W_bf[N][1024]^T (64 cols/block)
// Blocks [nrec, nrec+256): att[b,s] = esq_bf[b,s,:].h[b,:] (+ hc-fold on first 4/b)
__global__ __launch_bounds__(256) void k_rec(
    const unsigned short* __restrict__ A, const unsigned short* __restrict__ W,
    float* __restrict__ C, int N, int nrec,
    const unsigned short* __restrict__ esq, const float* __restrict__ h,
    const float* __restrict__ ctx, float* __restrict__ attL,
    unsigned short* __restrict__ hc) {
  __shared__ unsigned short As[32 * 1024];  // 64KB; att branch reuses 4KB as fp32 h
  int tid = threadIdx.x;
  int id = blockIdx.x;
  if (id < nrec) {
    {
      const uint4* src = (const uint4*)A;
      uint4* dst = (uint4*)As;
#pragma unroll
      for (int i = 0; i < 16; ++i) {
        int c = i * 256 + tid;
        int m = c >> 7, kc = c & 127;
        dst[m * 128 + (kc ^ (m & 7))] = src[c];  // XOR-swizzle per 16B chunk
      }
    }
    __syncthreads();
    int w = tid >> 6, l = tid & 63;
    int nb = id * 64 + w * 16;
    int fr = l & 15, fk8 = (l >> 4);  // k-offset = fk8*8
    const unsigned short* Wp = W + (size_t)(nb + fr) * 1024 + fk8 * 8;
    const bf16x8* Asv = (const bf16x8*)As;
    f32x4 acc0 = (f32x4){0.f, 0.f, 0.f, 0.f}, acc1 = acc0;
#pragma unroll 8
    for (int kt = 0; kt < 1024; kt += 32) {
      int kc8 = (kt >> 3) + fk8;
      bf16x8 bw = *(const bf16x8*)(Wp + kt);
      bf16x8 a0 = Asv[fr * 128 + (kc8 ^ (fr & 7))];
      bf16x8 a1 = Asv[(fr + 16) * 128 + (kc8 ^ (fr & 7))];
      acc0 = mfma_bf16(a0, bw, acc0);
      acc1 = mfma_bf16(a1, bw, acc1);
    }
    int col = nb + fr;
    int rb = (l >> 4) * 4;
#pragma unroll
    for (int r = 0; r < 4; ++r) {
      C[(size_t)(rb + r) * N + col] = acc0[r];
      C[(size_t)(rb + r + 16) * N + col] = acc1[r];
    }
  } else {
    float* hs = (float*)As;
    int a = id - nrec, b = a >> 3, sc = a & 7;
    for (int i = tid; i < 1024; i += 256) hs[i] = h[b * 1024 + i];
    __syncthreads();
    if (sc < 4) {
      int j = sc * 256 + tid;
      hc[b * 1024 + j] = f2bf(hs[j] + ctx[b * 1024 + j]);
    }
    int sg = tid >> 2, li = tid & 3;
    int s = sc * 64 + sg;
    const unsigned short* ep = esq + (size_t)(b * 512 + s) * 1024;
    float acc = 0.f;
#pragma unroll 8
    for (int i = 0; i < 32; ++i) {
      int k = (i * 4 + li) * 8;
      uint4 e = *(const uint4*)(ep + k);
      float4 h0 = *(const float4*)&hs[k];
      float4 h1 = *(const float4*)&hs[k + 4];
      acc += lof(e.x) * h0.x + hif(e.x) * h0.y + lof(e.y) * h0.z + hif(e.y) * h0.w +
             lof(e.z) * h1.x + hif(e.z) * h1.y + lof(e.w) * h1.z + hif(e.w) * h1.w;
    }
    acc += __shfl_xor(acc, 1);
    acc += __shfl_xor(acc, 2);
    if (li == 0) attL[b * 512 + s] = acc;
  }
}

// ---------------- ctx init (ctx = final encoder h) ----------------
__global__ void k_ctxinit(const float* __restrict__ h, float* __restrict__ ctx,
                          unsigned short* __restrict__ ctxbf) {
  int idx = blockIdx.x * 256 + threadIdx.x;
  float v = h[idx];
  ctx[idx] = v;
  ctxbf[idx] = f2bf(v);
}

// ---------------- softmax + ctx = w @ av_bf (vectorized, 512 blocks) -------
// Softmax max/sum bit-identical to the original k_ctxsm; ctx summation is
// regrouped into 32 s-groups x (8 lanes x 8 cols), fixed-order fp32 LDS
// reduce (same style validated in R10/R11/R12).
__global__ __launch_bounds__(256) void k_ctxsm(const float* __restrict__ attL,
                                               const unsigned short* __restrict__ av,
                                               float* __restrict__ ctx,
                                               unsigned short* __restrict__ ctxbf) {
  int jt = blockIdx.x, b = blockIdx.y;  // jt 0..15: 64-col slice
  __shared__ float w[512];
  __shared__ float wm[4];
  __shared__ float wsm[4];
  __shared__ float scr[256 * 8];  // 8KB partials
  int tid = threadIdx.x;
  float a0 = attL[b * Ss + tid * 2];
  float a1 = attL[b * Ss + tid * 2 + 1];
  float m = fmaxf(a0, a1);
  for (int d = 1; d < 64; d <<= 1) m = fmaxf(m, __shfl_xor(m, d));
  if ((tid & 63) == 0) wm[tid >> 6] = m;
  __syncthreads();
  m = fmaxf(fmaxf(wm[0], wm[1]), fmaxf(wm[2], wm[3]));
  float e0 = expf(a0 - m), e1 = expf(a1 - m);
  w[tid * 2] = e0;
  w[tid * 2 + 1] = e1;
  float ssum = e0 + e1;
  for (int d = 1; d < 64; d <<= 1) ssum += __shfl_xor(ssum, d);
  if ((tid & 63) == 0) wsm[tid >> 6] = ssum;
  __syncthreads();
  float scale = 1.f / (wsm[0] + wsm[1] + wsm[2] + wsm[3]);
  int g = tid & 7, si = tid >> 3;  // 8 col-groups of 8 x 32 s-groups
  const unsigned short* avp = av + (size_t)(b * Ss) * Hh + jt * 64 + g * 8;
  float a8[8] = {0.f, 0.f, 0.f, 0.f, 0.f, 0.f, 0.f, 0.f};
#pragma unroll 8
  for (int s = si; s < 512; s += 32) {
    float wv = w[s];
    uint4 e = *(const uint4*)(avp + (size_t)s * Hh);
    a8[0] += wv * lof(e.x); a8[1] += wv * hif(e.x);
    a8[2] += wv * lof(e.y); a8[3] += wv * hif(e.y);
    a8[4] += wv * lof(e.z); a8[5] += wv * hif(e.z);
    a8[6] += wv * lof(e.w); a8[7] += wv * hif(e.w);
  }
#pragma unroll
  for (int k2 = 0; k2 < 8; ++k2) scr[tid * 8 + k2] = a8[k2];
  __syncthreads();
  if (tid < 64) {
    int g2 = tid >> 3, k2 = tid & 7;
    float p = 0.f;
#pragma unroll
    for (int si2 = 0; si2 < 32; ++si2) p += scr[(si2 * 8 + g2) * 8 + k2];
    float v = p * scale;
    int j3 = b * Hh + jt * 64 + tid;
    ctx[j3] = v;
    ctxbf[j3] = f2bf(v);
  }
}

// ---------------- host ----------------
extern "C" void kernel_launch(void* const* d_in, const int* in_sizes, int n_in,
                              void* d_out, int out_size, void* d_ws, size_t ws_size,
                              hipStream_t stream) {
  (void)in_sizes; (void)n_in; (void)out_size; (void)ws_size;
  const int*   src_chars = (const int*)d_in[0];
  const int*   src_langs = (const int*)d_in[1];
  const int*   tgt_chars = (const int*)d_in[2];
  const float* char_emb  = (const float*)d_in[3];
  const float* lang_emb  = (const float*)d_in[4];
  const float* fc_W  = (const float*)d_in[5];
  const float* fc_b  = (const float*)d_in[6];
  const float* enc_Wi = (const float*)d_in[7];
  const float* enc_Wh = (const float*)d_in[8];
  const float* enc_bi = (const float*)d_in[9];
  const float* enc_bh = (const float*)d_in[10];
  const float* dec_Wi = (const float*)d_in[11];
  const float* dec_Wh = (const float*)d_in[12];
  const float* dec_bi = (const float*)d_in[13];
  const float* dec_bh = (const float*)d_in[14];
  const float* Wq  = (const float*)d_in[15];
  const float* Wk  = (const float*)d_in[16];
  const float* Wcs = (const float*)d_in[17];
  const float* W1 = (const float*)d_in[18];
  const float* b1 = (const float*)d_in[19];
  const float* W2 = (const float*)d_in[20];
  const float* b2 = (const float*)d_in[21];
  const float* W3 = (const float*)d_in[22];
  float* out = (float*)d_out;

  char* ws = (char*)d_ws;
  unsigned short* esbf  = (unsigned short*)(ws + O_ESBF);
  unsigned short* esq   = (unsigned short*)(ws + O_ESQ);
  unsigned short* avbf  = (unsigned short*)(ws + O_AVBF);
  unsigned short* hcbf  = (unsigned short*)(ws + O_HCBF);
  unsigned short* WheB  = (unsigned short*)(ws + O_WHE);
  unsigned short* WhdB  = (unsigned short*)(ws + O_WHD);
  unsigned short* WicB  = (unsigned short*)(ws + O_WIC);
  unsigned short* WkB   = (unsigned short*)(ws + O_WKB);
  unsigned short* WqTB  = (unsigned short*)(ws + O_WQT);
  unsigned short* W1B   = (unsigned short*)(ws + O_W1B);
  unsigned short* W2B   = (unsigned short*)(ws + O_W2B);
  unsigned short* W3B   = (unsigned short*)(ws + O_W3B);
  float* xcat   = (float*)(ws + O_XCAT);
  float* embfc  = (float*)(ws + O_EMBFC);
  float* gitab  = (float*)(ws + O_GITAB);
  float* avtab  = (float*)(ws + O_AVTAB);
  float* dgixt  = (float*)(ws + O_DGIXT);
  float* ghbuf  = (float*)(ws + O_GH);
  float* h      = (float*)(ws + O_H);
  unsigned short* hbf   = (unsigned short*)(ws + O_HBF);
  float* ctx    = (float*)(ws + O_CTX);
  unsigned short* ctxbf = (unsigned short*)(ws + O_CTXBF);
  float* attL   = (float*)(ws + O_ATTL);
  unsigned short* G1 = esq;   // alias: dead after decoder
  unsigned short* G2 = avbf;  // alias: dead after decoder
  int* cltab = (int*)(ws + O_GI);                               // 64KB
  unsigned short* hbf2 = (unsigned short*)(ws + O_GI + 65536);  // 64KB enc dbuf
  int* bar = (int*)(ws + O_GI + 131072);                        // enc barrier

  dim3 blk(256);

  // ---- tables (fp32) ----
  k_xcat<<<640, blk, 0, stream>>>(char_emb, lang_emb, xcat);
  k_cltab<<<64, blk, 0, stream>>>(src_chars, src_langs, cltab, bar);
  k_gemm<true><<<dim3(4, 5), blk, 0, stream>>>(xcat, 1024, fc_W, 1024, fc_b, embfc, 512, 1024);
  k_gemm<true><<<dim3(24, 5), blk, 0, stream>>>(embfc, 512, enc_Wi, 512, enc_bi, gitab, H3, 512);
  k_gemm<false><<<dim3(8, 5), blk, 0, stream>>>(embfc, 512, Wcs, 512, nullptr, avtab, Hh, 512);
  k_gemm<true><<<dim3(24, 1), blk, 0, stream>>>(embfc + 512 * 512, 512, dec_Wi, 1536, dec_bi,
                                                dgixt, H3, 512);
  // ---- weight conversions ----
  k_cvt<<<1536, blk, 0, stream>>>(enc_Wh, 1024, 10, WheB);
  k_cvt<<<1536, blk, 0, stream>>>(dec_Wh, 1024, 10, WhdB);
  k_cvt<<<1536, blk, 0, stream>>>(dec_Wi + 512, 1536, 10, WicB);
  k_cvt<<<512,  blk, 0, stream>>>(Wk, 1024, 10, WkB);
  k_cvt<<<2048, blk, 0, stream>>>(W1, 1024, 10, W1B);
  k_cvt<<<4096, blk, 0, stream>>>(W2, 4096, 12, W2B);
  k_cvt<<<128,  blk, 0, stream>>>(W3, 2048, 11, W3B);
  k_transcvt<<<dim3(32, 32), dim3(32, 8), 0, stream>>>(Wq, WqTB);

  // ---- encoder scan: persistent cooperative kernel, custom barrier ----
  {
    const unsigned short* p_whe = WheB;
    const float* p_git = gitab;
    const int* p_cl = cltab;
    const float* p_bh = enc_bh;
    float* p_h = h;
    unsigned short* p_h0 = hbf;   // s even writes hbf (R6 parity)
    unsigned short* p_h1 = hbf2;
    unsigned short* p_esb = esbf;
    int* p_bar = bar;
    void* kargs[] = {(void*)&p_whe, (void*)&p_git, (void*)&p_cl, (void*)&p_bh,
                     (void*)&p_h, (void*)&p_h0, (void*)&p_h1, (void*)&p_esb,
                     (void*)&p_bar};
    hipLaunchCooperativeKernel((const void*)k_enc_pers, dim3(NBE), dim3(512), kargs, 0, stream);
  }

  // ---- esq = es @ Wq (for att = esq.h); av = es @ Wk^T + avtab ----
  k_bgemm<0, false, false><<<dim3(8, 128), blk, 0, stream>>>(
      esbf, 1024, WqTB, 1024, nullptr, esq, 1024, 1024, nullptr, nullptr, nullptr);
  k_bgemm<1, false, false><<<dim3(8, 128), blk, 0, stream>>>(
      esbf, 1024, WkB, 1024, nullptr, avbf, 1024, 1024, avtab, src_langs, src_chars);

  // ---- decoder init: h0 = gru(0, [start_emb, ctx0]) ----
  k_ctxinit<<<128, blk, 0, stream>>>(h, ctx, ctxbf);
  k_step<1><<<128, 512, 0, stream>>>(WicB, ctxbf, dgixt, tgt_chars, nullptr, dec_bh,
                                     h, hbf, nullptr, 0, 3);

  // ---- decoder scan: [gh + att + hc] / ctxsm / [gi + gates] ----
  for (int t = 0; t < Tt; ++t) {
    k_rec<<<304, blk, 0, stream>>>(hbf, WhdB, ghbuf, H3, 48,
                                   esq, h, ctx, attL, hcbf + (size_t)t * Bb * Hh);
    if (t == Tt - 1) break;
    k_ctxsm<<<dim3(16, 32), blk, 0, stream>>>(attL, avbf, ctx, ctxbf);
    k_step<1><<<128, 512, 0, stream>>>(WicB, ctxbf, dgixt, tgt_chars, ghbuf, dec_bh,
                                       h, hbf, nullptr, t, 0);
  }

  // ---- MLP: scores = relu(relu(hc@W1^T+b1)@W2^T+b2)@W3^T ----
  k_bgemm<0, true, true><<<dim3(32, 32), blk, 0, stream>>>(
      hcbf, 1024, W1B, 1024, b1, G1, 4096, 1024, nullptr, nullptr, nullptr);
  k_bgemm<0, true, true><<<dim3(16, 32), blk, 0, stream>>>(
      G1, 4096, W2B, 4096, b2, G2, 2048, 4096, nullptr, nullptr, nullptr);
  k_bgemm<2, false, false><<<dim3(1, 32), blk, 0, stream>>>(
      G2, 2048, W3B, 2048, nullptr, out, 0, 2048, nullptr, nullptr, nullptr);
}